// Round 7
// baseline (81.998 us; speedup 1.0000x reference)
//
#include <hip/hip_runtime.h>

// Problem constants
#define DL 16384   // D*L tokens
#define LL 2048
#define NQB 64     // NQ
#define QBS 32     // QB
#define KBS 128    // KB

typedef __attribute__((ext_vector_type(8))) short short8;
typedef __attribute__((ext_vector_type(4))) short short4v;
typedef __attribute__((ext_vector_type(4))) float f32x4;

__device__ __forceinline__ float sigmoidf_(float x) { return 1.f / (1.f + expf(-x)); }

__device__ __forceinline__ short f2bf(float f) {
    union { float f; unsigned u; } v; v.f = f;
    unsigned r = (v.u + 0x7FFFu + ((v.u >> 16) & 1u)) >> 16;
    return (short)r;
}
__device__ __forceinline__ unsigned f2bfu(float f) {
    union { float f; unsigned u; } v; v.f = f;
    return (v.u + 0x7FFFu + ((v.u >> 16) & 1u)) >> 16;
}
__device__ __forceinline__ float bf2f(short h) {
    union { unsigned u; float f; } v; v.u = ((unsigned)(unsigned short)h) << 16;
    return v.f;
}
__device__ __forceinline__ unsigned packbf(float a, float b) {
    return (f2bfu(a) & 0xFFFFu) | (f2bfu(b) << 16);
}

// fragment helpers (cl = lane&15, kg = lane>>4 must be in scope)
#define AFRAG(buf, stride, r0, kk) (*(const short8*)&(buf)[(size_t)((r0) + cl) * (stride) + (kk) * 32 + kg * 8])
#define WFRAG(Wt, K, n0, kk) (*(const short8*)((Wt) + (size_t)((n0) + cl) * (K) + (kk) * 32 + kg * 8))
#define MFMA(acc, a, b) acc = __builtin_amdgcn_mfma_f32_16x16x32_bf16(a, b, acc, 0, 0, 0)

// ---------------------------------------------------------------------------
// Kernel 0: fused prep.
//   blocks 0..16  : weight transpose to bf16 [N][K] via LDS tile
//   blocks 17..528: pair-bias  BBt[n][h][i=q:32][j=key:128] bf16 (4 q-rows/block)
//   Z reads fully coalesced: 4 lanes cooperate per (i,j) pair (64 B row).
// ---------------------------------------------------------------------------
__global__ __launch_bounds__(256) void k_prep(
    const float* __restrict__ W0, const float* __restrict__ W1, const float* __restrict__ W2,
    const float* __restrict__ W3, const float* __restrict__ W4, const float* __restrict__ W5,
    const float* __restrict__ W6, const float* __restrict__ W7, const float* __restrict__ W8,
    const float* __restrict__ W9, const float* __restrict__ W10,
    const float* __restrict__ Wsw, const float* __restrict__ Wlin, const float* __restrict__ Wout2,
    const float* __restrict__ Z, const float* __restrict__ g16, const float* __restrict__ b16,
    const float* __restrict__ Wb,
    short* __restrict__ wout, short* __restrict__ BBt)
{
    __shared__ float sW[128 * 128];          // 64 KB (weight-transpose path)
    __shared__ float sWb[64], sg[16], sb[16];
    __shared__ short sT[4 * 4 * 128];        // bias staging [h][il][j]
    const int b = blockIdx.x;
    const int tid = threadIdx.x;

    if (b < 17) {
        const float* srcs[14] = {W0,W1,W2,W3,W4,W5,W6,W7,W8,W9,W10,Wsw,Wlin,Wout2};
        const int sel[17]  = {0,1,2,3,4,5,6,7,8,9,10,11,11,12,12,13,13};
        const int soff[17] = {0,0,0,0,0,0,0,0,0,0,0, 0,128, 0,128, 0,16384};
        const int sN[17]   = {128,128,128,128,128,128,128,128,128,128,128, 256,256,256,256, 128,128};
        const int doff[17] = {0,16384,32768,49152,65536,81920,98304,114688,131072,147456,163840,
                              180224,196608, 212992,229376, 245760,245888};
        const int dK[17]   = {128,128,128,128,128,128,128,128,128,128,128, 128,128,128,128, 256,256};
        const float* src = srcs[sel[b]] + soff[b];
        const int srcN = sN[b];
        short* dst = wout + doff[b];
        const int dstK = dK[b];
        {   // coalesced load of 128x128 f32 tile
            const int r = tid >> 1, ch = (tid & 1) * 64;
            #pragma unroll
            for (int u = 0; u < 16; ++u) {
                float4 v = *(const float4*)(src + (size_t)r * srcN + ch + u * 4);
                *(float4*)&sW[r * 128 + ch + u * 4] = v;
            }
        }
        __syncthreads();
        {   // coalesced transposed bf16 write
            const int o = tid >> 1, kh = (tid & 1) * 64;
            #pragma unroll
            for (int u8 = 0; u8 < 8; ++u8) {
                short8 pk;
                #pragma unroll
                for (int e = 0; e < 8; ++e)
                    pk[e] = f2bf(sW[(kh + u8 * 8 + e) * 128 + o]);
                *(short8*)(dst + (size_t)o * dstK + kh + u8 * 8) = pk;
            }
        }
    } else {
        const int bb = b - 17;           // 0..511
        const int n = bb >> 3;           // 0..63
        const int io = (bb & 7) * 4;     // 4-row slice
        if (tid < 64) sWb[tid] = Wb[tid];
        if (tid < 16) { sg[tid] = g16[tid]; sb[tid] = b16[tid]; }
        __syncthreads();
        const int q4 = tid & 3;          // cp quarter
        #pragma unroll
        for (int p = 0; p < 8; ++p) {
            int pairIdx = p * 64 + (tid >> 2);   // 0..511
            int il = pairIdx >> 7, j = pairIdx & 127;
            int i = io + il;
            int kr = n * 32 - 48 + j;
            int kc = min(max(kr, 0), LL - 1);
            // 4 lanes read 16B each of the 64B row -> coalesced
            float4 zv = *(const float4*)(Z + ((long)(n * 32 + i) * LL + kc) * 16 + q4 * 4);
            float sm = zv.x + zv.y + zv.z + zv.w;
            float sq = fmaf(zv.x, zv.x, fmaf(zv.y, zv.y, fmaf(zv.z, zv.z, zv.w * zv.w)));
            sm += __shfl_xor(sm, 1); sm += __shfl_xor(sm, 2);
            sq += __shfl_xor(sq, 1); sq += __shfl_xor(sq, 2);
            float m = sm * (1.f / 16.f);
            float rs = rsqrtf(sq * (1.f / 16.f) - m * m + 1e-5f);
            float zn[4];
            zn[0] = (zv.x - m) * rs * sg[q4 * 4 + 0] + sb[q4 * 4 + 0];
            zn[1] = (zv.y - m) * rs * sg[q4 * 4 + 1] + sb[q4 * 4 + 1];
            zn[2] = (zv.z - m) * rs * sg[q4 * 4 + 2] + sb[q4 * 4 + 2];
            zn[3] = (zv.w - m) * rs * sg[q4 * 4 + 3] + sb[q4 * 4 + 3];
            float b0 = 0.f, b1 = 0.f, b2 = 0.f, b3 = 0.f;
            #pragma unroll
            for (int e = 0; e < 4; ++e) {
                int cp = q4 * 4 + e;
                b0 = fmaf(zn[e], sWb[cp * 4 + 0], b0);
                b1 = fmaf(zn[e], sWb[cp * 4 + 1], b1);
                b2 = fmaf(zn[e], sWb[cp * 4 + 2], b2);
                b3 = fmaf(zn[e], sWb[cp * 4 + 3], b3);
            }
            b0 += __shfl_xor(b0, 1); b0 += __shfl_xor(b0, 2);
            b1 += __shfl_xor(b1, 1); b1 += __shfl_xor(b1, 2);
            b2 += __shfl_xor(b2, 1); b2 += __shfl_xor(b2, 2);
            b3 += __shfl_xor(b3, 1); b3 += __shfl_xor(b3, 2);
            float vh = (q4 == 0) ? b0 : (q4 == 1) ? b1 : (q4 == 2) ? b2 : b3;
            sT[(q4 * 4 + il) * 128 + j] = f2bf(vh);
        }
        __syncthreads();
        #pragma unroll
        for (int rr = 0; rr < 2; ++rr) {
            int cid = tid + rr * 256;    // 0..511
            int hh = cid >> 7, r2 = cid & 127;
            int il = r2 >> 5, jb = (r2 & 31) * 4;
            short4v pk;
            #pragma unroll
            for (int e = 0; e < 4; ++e) pk[e] = sT[(hh * 4 + il) * 128 + jb + e];
            *(short4v*)(BBt + (((size_t)n * 4 + hh) * 32 + io + il) * 128 + jb) = pk;
        }
    }
}

// ---------------------------------------------------------------------------
// Kernel 1: adaLN1 + QKV+G projections via MFMA.
// 32 tokens / block, 512 threads (8 waves): wave w owns col-tile n0=w*16.
// ---------------------------------------------------------------------------
__global__ __launch_bounds__(512) void k_adaln_qkvg(
    const float* __restrict__ A_I, const float* __restrict__ S_I,
    const short* __restrict__ Wg1t, const short* __restrict__ Ws1t,
    const short* __restrict__ Wqt, const short* __restrict__ Wkt,
    const short* __restrict__ Wvt, const short* __restrict__ Wgat,
    const float* __restrict__ bg1, const float* __restrict__ bq,
    short* __restrict__ Qo, short* __restrict__ Ko, short* __restrict__ Vo, short* __restrict__ Go)
{
    __shared__ short sAr[32 * 136];   // raw A bf16
    __shared__ short sSn[32 * 136];   // LN(S) bf16
    __shared__ short sAn[32 * 136];   // An bf16
    __shared__ float sMean[32], sRstd[32];
    const int tid = threadIdx.x;
    const int lane = tid & 63;
    const long t0 = (long)blockIdx.x * 32;

    {   // P0
        const int row = tid >> 4, seg = tid & 15;
        const float* ap = A_I + (t0 + row) * 128 + seg * 8;
        const float* sp = S_I + (t0 + row) * 128 + seg * 8;
        float av[8], sv[8];
        #pragma unroll
        for (int u = 0; u < 2; ++u) {
            float4 a4 = ((const float4*)ap)[u];
            float4 s4 = ((const float4*)sp)[u];
            av[4*u] = a4.x; av[4*u+1] = a4.y; av[4*u+2] = a4.z; av[4*u+3] = a4.w;
            sv[4*u] = s4.x; sv[4*u+1] = s4.y; sv[4*u+2] = s4.z; sv[4*u+3] = s4.w;
        }
        float am = 0.f, aq = 0.f, sm = 0.f, sq = 0.f;
        #pragma unroll
        for (int u = 0; u < 8; ++u) {
            am += av[u]; aq = fmaf(av[u], av[u], aq);
            sm += sv[u]; sq = fmaf(sv[u], sv[u], sq);
        }
        am += __shfl_xor(am, 1); am += __shfl_xor(am, 2); am += __shfl_xor(am, 4); am += __shfl_xor(am, 8);
        aq += __shfl_xor(aq, 1); aq += __shfl_xor(aq, 2); aq += __shfl_xor(aq, 4); aq += __shfl_xor(aq, 8);
        sm += __shfl_xor(sm, 1); sm += __shfl_xor(sm, 2); sm += __shfl_xor(sm, 4); sm += __shfl_xor(sm, 8);
        sq += __shfl_xor(sq, 1); sq += __shfl_xor(sq, 2); sq += __shfl_xor(sq, 4); sq += __shfl_xor(sq, 8);
        float amean = am * (1.f / 128.f);
        float arstd = rsqrtf(aq * (1.f / 128.f) - amean * amean + 1e-5f);
        float smean = sm * (1.f / 128.f);
        float srstd = rsqrtf(sq * (1.f / 128.f) - smean * smean + 1e-5f);
        if ((tid & 15) == 0) { sMean[row] = amean; sRstd[row] = arstd; }
        short8 pa, ps;
        #pragma unroll
        for (int e = 0; e < 8; ++e) {
            pa[e] = f2bf(av[e]);
            ps[e] = f2bf((sv[e] - smean) * srstd);
        }
        *(short8*)&sAr[row * 136 + seg * 8] = pa;
        *(short8*)&sSn[row * 136 + seg * 8] = ps;
    }
    __syncthreads();
    const int w = tid >> 6;
    const int n0 = w * 16;
    const int cl = lane & 15, kg = lane >> 4;
    {   // P1: An
        short8 wg[4], wsf[4];
        #pragma unroll
        for (int kk = 0; kk < 4; ++kk) {
            wg[kk]  = WFRAG(Wg1t, 128, n0, kk);
            wsf[kk] = WFRAG(Ws1t, 128, n0, kk);
        }
        #pragma unroll
        for (int mt = 0; mt < 2; ++mt) {
            f32x4 ag = {0.f, 0.f, 0.f, 0.f}, as = {0.f, 0.f, 0.f, 0.f};
            #pragma unroll
            for (int kk = 0; kk < 4; ++kk) {
                short8 a = AFRAG(sSn, 136, mt * 16, kk);
                MFMA(ag, a, wg[kk]);
                MFMA(as, a, wsf[kk]);
            }
            const int col = n0 + cl;
            float bgc = bg1[col];
            #pragma unroll
            for (int i = 0; i < 4; ++i) {
                int r = mt * 16 + kg * 4 + i;
                float an = (bf2f(sAr[r * 136 + col]) - sMean[r]) * sRstd[r];
                float An = sigmoidf_(ag[i] + bgc) * an + as[i];
                sAn[r * 136 + col] = f2bf(An);
            }
        }
    }
    __syncthreads();
    {   // P2: Q,K,V,G
        const float SCL = 0.17677669529663687f;  // 1/sqrt(32)
        short8 af[2][4];
        #pragma unroll
        for (int mt = 0; mt < 2; ++mt)
            #pragma unroll
            for (int kk = 0; kk < 4; ++kk)
                af[mt][kk] = AFRAG(sAn, 136, mt * 16, kk);
        #pragma unroll
        for (int m = 0; m < 4; ++m) {
            const short* Wt = (m == 0) ? Wqt : (m == 1) ? Wkt : (m == 2) ? Wvt : Wgat;
            short8 wf[4];
            #pragma unroll
            for (int kk = 0; kk < 4; ++kk) wf[kk] = WFRAG(Wt, 128, n0, kk);
            #pragma unroll
            for (int mt = 0; mt < 2; ++mt) {
                f32x4 acc = {0.f, 0.f, 0.f, 0.f};
                #pragma unroll
                for (int kk = 0; kk < 4; ++kk) MFMA(acc, af[mt][kk], wf[kk]);
                const int col = n0 + cl;
                #pragma unroll
                for (int i = 0; i < 4; ++i) {
                    long t = t0 + mt * 16 + kg * 4 + i;
                    float v = acc[i];
                    if (m == 0)      Qo[t * 128 + col] = f2bf((v + bq[col]) * SCL);
                    else if (m == 1) Ko[t * 128 + col] = f2bf(v);
                    else if (m == 2) Vo[t * 128 + col] = f2bf(v);
                    else             Go[t * 128 + col] = f2bf(sigmoidf_(v));
                }
            }
        }
    }
}

// ---------------------------------------------------------------------------
// Kernel 3: windowed attention, block = (n, d, mt-quarter), wave = head.
// Swapped QK^T (S^T = K·Q) -> P fully in registers; shfl pack-exchange feeds
// PV's B operand directly.  Only V^T lives in LDS (34.8 KB, 1 barrier).
// ---------------------------------------------------------------------------
__global__ __launch_bounds__(256) void k_attn(
    const short* __restrict__ Qg, const short* __restrict__ Kg, const short* __restrict__ Vg,
    const short* __restrict__ Gg, const short* __restrict__ BBt, const float* __restrict__ maskK,
    short* __restrict__ AFo)
{
    __shared__ short vts[4 * 32 * 136];   // per-head V^T [c][key]
    const int n = blockIdx.x, d = blockIdx.y, mt = blockIdx.z;
    const int tid = threadIdx.x;
    const int lane = tid & 63;
    const int h = tid >> 6;
    const long tb = (long)d * LL;
    const int kbase = n * 32 - 48;
    short* vtsH = vts + h * 4352;
    const int cl = lane & 15, kg = lane >> 4;

    {   // V transpose: lane handles keys 2*lane, 2*lane+1, channels 0..31 of head h
        const int j0 = lane * 2;
        int kc0 = min(max(kbase + j0, 0), LL - 1);
        int kc1 = min(max(kbase + j0 + 1, 0), LL - 1);
        const short8* p0 = (const short8*)(Vg + (tb + kc0) * 128 + h * 32);
        const short8* p1 = (const short8*)(Vg + (tb + kc1) * 128 + h * 32);
        short8 ev[4] = {p0[0], p0[1], p0[2], p0[3]};
        short8 ov[4] = {p1[0], p1[1], p1[2], p1[3]};
        #pragma unroll
        for (int g = 0; g < 4; ++g)
            #pragma unroll
            for (int e = 0; e < 8; ++e)
                *(unsigned*)&vtsH[(g * 8 + e) * 136 + j0] =
                    (unsigned)(unsigned short)ev[g][e] | ((unsigned)(unsigned short)ov[g][e] << 16);
    }

    float sc[8][4];
    {   // swapped QK^T: lane(cl,kg) -> q = mt*16+cl, keys nt*16+kg*4+i
        short8 qf = *(const short8*)(Qg + (tb + n * 32 + mt * 16 + cl) * 128 + h * 32 + kg * 8);
        #pragma unroll
        for (int nt = 0; nt < 8; ++nt) {
            int kc = min(max(kbase + nt * 16 + cl, 0), LL - 1);
            short8 kf = *(const short8*)(Kg + (tb + kc) * 128 + h * 32 + kg * 8);
            f32x4 s = {0.f, 0.f, 0.f, 0.f};
            MFMA(s, kf, qf);                   // A=K rows (m=key), B=Q rows (n=q)
            float4 mk4 = *(const float4*)(maskK + n * 128 + nt * 16 + kg * 4);
            short4v bfr = *(const short4v*)(BBt + (((size_t)n * 4 + h) * 32 + mt * 16 + cl) * 128 + nt * 16 + kg * 4);
            #pragma unroll
            for (int i = 0; i < 4; ++i)
                sc[nt][i] = s[i] + bf2f(bfr[i]) - mk4[i] * 1e9f;
        }
    }
    unsigned bfrag[4][4];   // [32-key chunk][4 packed u32] — PV B-operand
    {   // in-register softmax over this lane's 32 keys + cross-kg reduce
        float mx = sc[0][0];
        #pragma unroll
        for (int nt = 0; nt < 8; ++nt)
            #pragma unroll
            for (int i = 0; i < 4; ++i) mx = fmaxf(mx, sc[nt][i]);
        mx = fmaxf(mx, __shfl_xor(mx, 16));
        mx = fmaxf(mx, __shfl_xor(mx, 32));
        float sm = 0.f;
        #pragma unroll
        for (int nt = 0; nt < 8; ++nt)
            #pragma unroll
            for (int i = 0; i < 4; ++i) {
                float p = __expf(sc[nt][i] - mx);
                sc[nt][i] = p; sm += p;
            }
        sm += __shfl_xor(sm, 16);
        sm += __shfl_xor(sm, 32);
        float inv = 1.f / sm;
        // pack-exchange: redistribute P from C-layout (keys kg*4+i per 16-tile)
        // to B-frag layout (keys kg*8..+7 per 32-chunk) via xor32 then xor16.
        #pragma unroll
        for (int c2 = 0; c2 < 4; ++c2) {
            unsigned E0 = packbf(sc[2*c2][0] * inv, sc[2*c2][1] * inv);
            unsigned E1 = packbf(sc[2*c2][2] * inv, sc[2*c2][3] * inv);
            unsigned O0 = packbf(sc[2*c2+1][0] * inv, sc[2*c2+1][1] * inv);
            unsigned O1 = packbf(sc[2*c2+1][2] * inv, sc[2*c2+1][3] * inv);
            unsigned t0 = (kg < 2) ? O0 : E0;
            unsigned t1 = (kg < 2) ? O1 : E1;
            unsigned r10 = __shfl_xor((int)t0, 32);
            unsigned r11 = __shfl_xor((int)t1, 32);
            unsigned u0 = (kg == 0 || kg == 3) ? r10 : (kg == 1 ? E0 : O0);
            unsigned u1 = (kg == 0 || kg == 3) ? r11 : (kg == 1 ? E1 : O1);
            unsigned r20 = __shfl_xor((int)u0, 16);
            unsigned r21 = __shfl_xor((int)u1, 16);
            bfrag[c2][0] = (kg == 0) ? E0 : (kg == 2) ? r10 : r20;
            bfrag[c2][1] = (kg == 0) ? E1 : (kg == 2) ? r11 : r21;
            bfrag[c2][2] = (kg == 0) ? r20 : (kg == 1) ? r10 : (kg == 2) ? r20 : O0;
            bfrag[c2][3] = (kg == 0) ? r21 : (kg == 1) ? r11 : (kg == 2) ? r21 : O1;
        }
    }
    __syncthreads();
    {   // PV: A = V^T rows (m=c), B = P regs (n=q); C[c][q] -> packed 8B stores
        #pragma unroll
        for (int ct = 0; ct < 2; ++ct) {
            f32x4 acc = {0.f, 0.f, 0.f, 0.f};
            #pragma unroll
            for (int c2 = 0; c2 < 4; ++c2) {
                short8 a = *(const short8*)&vtsH[(ct * 16 + cl) * 136 + c2 * 32 + kg * 8];
                union { unsigned u[4]; short8 s; } bb;
                bb.u[0] = bfrag[c2][0]; bb.u[1] = bfrag[c2][1];
                bb.u[2] = bfrag[c2][2]; bb.u[3] = bfrag[c2][3];
                MFMA(acc, a, bb.s);
            }
            long t = tb + n * 32 + mt * 16 + cl;
            const int c0 = h * 32 + ct * 16 + kg * 4;
            short4v g4 = *(const short4v*)(Gg + t * 128 + c0);
            short4v o4;
            #pragma unroll
            for (int i = 0; i < 4; ++i) o4[i] = f2bf(bf2f(g4[i]) * acc[i]);
            *(short4v*)(AFo + t * 128 + c0) = o4;
        }
    }
}

// ---------------------------------------------------------------------------
// Kernel 4: fused post: af@Wa gate residual + adaLN2 + SwiGLU + ct-gate.
// 32 tokens / block, 512 threads (8 waves): wave w owns col-tile n0=w*16.
// ---------------------------------------------------------------------------
__global__ __launch_bounds__(512) void k_postf(
    const short* __restrict__ AF, const float* __restrict__ S_I, const float* __restrict__ A_I,
    const short* __restrict__ Wat, const short* __restrict__ Wopt, const short* __restrict__ ctWgt,
    const short* __restrict__ Wg2t, const short* __restrict__ Ws2t,
    const short* __restrict__ Wswt, const short* __restrict__ Wlint, const short* __restrict__ Wout2t,
    const float* __restrict__ bop, const float* __restrict__ ctbg, const float* __restrict__ bg2,
    float* __restrict__ Out)
{
    __shared__ __align__(16) char smem[43264];
    short* sAF  = (short*)smem;              // [32][136] bf16 AF       -> reused as sAn2
    short* sS   = (short*)(smem + 8704);     // [32][136] bf16 raw S    -> reused by sB
    short* sSn  = (short*)(smem + 17408);    // [32][136] bf16 LN(S)    (partly reused by sB)
    float* sA   = (float*)(smem + 26112);    // [32][132] f32: raw A_I in P0, final A after P2
    float* sMean = (float*)(smem + 43008);   // [32]
    float* sRstd = (float*)(smem + 43136);   // [32]
    short* sAn2 = sAF;                       // [32][136] bf16 an2
    short* sB   = (short*)(smem + 8704);     // [32][264] bf16 b

    const int tid = threadIdx.x;
    const int lane = tid & 63;
    const long t0 = (long)blockIdx.x * 32;

    {   // P0
        const int row = tid >> 4, seg = tid & 15;
        *(short8*)&sAF[row * 136 + seg * 8] =
            *(const short8*)(AF + (t0 + row) * 128 + seg * 8);
        const float* apI = A_I + (t0 + row) * 128 + seg * 8;
        #pragma unroll
        for (int u = 0; u < 2; ++u)
            *(float4*)&sA[row * 132 + seg * 8 + u * 4] = ((const float4*)apI)[u];
        const float* sp = S_I + (t0 + row) * 128 + seg * 8;
        float sv[8];
        #pragma unroll
        for (int u = 0; u < 2; ++u) {
            float4 s4 = ((const float4*)sp)[u];
            sv[4*u] = s4.x; sv[4*u+1] = s4.y; sv[4*u+2] = s4.z; sv[4*u+3] = s4.w;
        }
        float sm = 0.f, sq = 0.f;
        #pragma unroll
        for (int u = 0; u < 8; ++u) { sm += sv[u]; sq = fmaf(sv[u], sv[u], sq); }
        sm += __shfl_xor(sm, 1); sm += __shfl_xor(sm, 2); sm += __shfl_xor(sm, 4); sm += __shfl_xor(sm, 8);
        sq += __shfl_xor(sq, 1); sq += __shfl_xor(sq, 2); sq += __shfl_xor(sq, 4); sq += __shfl_xor(sq, 8);
        float smean = sm * (1.f / 128.f);
        float srstd = rsqrtf(sq * (1.f / 128.f) - smean * smean + 1e-5f);
        short8 pr, pn;
        #pragma unroll
        for (int e = 0; e < 8; ++e) {
            float s = sv[e];
            pr[e] = f2bf(s);
            pn[e] = f2bf((s - smean) * srstd);
        }
        *(short8*)&sS [row * 136 + seg * 8] = pr;
        *(short8*)&sSn[row * 136 + seg * 8] = pn;
    }
    __syncthreads();
    const int w = tid >> 6;
    const int n0 = w * 16;
    const int cl = lane & 15, kg = lane >> 4;
    float g2s[8];

    {   // P2
        short8 wA[4], wO[4], wG[4];
        #pragma unroll
        for (int kk = 0; kk < 4; ++kk) {
            wA[kk] = WFRAG(Wat, 128, n0, kk);
            wO[kk] = WFRAG(Wopt, 128, n0, kk);
            wG[kk] = WFRAG(ctWgt, 128, n0, kk);
        }
        #pragma unroll
        for (int mt = 0; mt < 2; ++mt) {
            f32x4 aA = {0.f,0.f,0.f,0.f}, aO = {0.f,0.f,0.f,0.f}, aG = {0.f,0.f,0.f,0.f};
            #pragma unroll
            for (int kk = 0; kk < 4; ++kk) {
                short8 af = AFRAG(sAF, 136, mt * 16, kk);
                short8 sf = AFRAG(sS, 136, mt * 16, kk);
                MFMA(aA, af, wA[kk]);
                MFMA(aO, sf, wO[kk]);
                MFMA(aG, sf, wG[kk]);
            }
            const int col = n0 + cl;
            float bopc = bop[col], ctc = ctbg[col];
            #pragma unroll
            for (int i = 0; i < 4; ++i) {
                int r = mt * 16 + kg * 4 + i;
                float Aval = sA[r * 132 + col] + sigmoidf_(aO[i] + bopc) * aA[i];
                sA[r * 132 + col] = Aval;
                g2s[mt * 4 + i] = sigmoidf_(aG[i] + ctc);
            }
        }
    }
    __syncthreads();
    {   // P3: LN stats of A rows
        const int row = tid >> 4, seg = tid & 15;
        float m = 0.f, q = 0.f;
        #pragma unroll
        for (int u = 0; u < 2; ++u) {
            float4 v = *(const float4*)&sA[row * 132 + seg * 8 + u * 4];
            m += v.x + v.y + v.z + v.w;
            q = fmaf(v.x, v.x, q); q = fmaf(v.y, v.y, q);
            q = fmaf(v.z, v.z, q); q = fmaf(v.w, v.w, q);
        }
        m += __shfl_xor(m, 1); m += __shfl_xor(m, 2); m += __shfl_xor(m, 4); m += __shfl_xor(m, 8);
        q += __shfl_xor(q, 1); q += __shfl_xor(q, 2); q += __shfl_xor(q, 4); q += __shfl_xor(q, 8);
        float mean = m * (1.f / 128.f);
        float rstd = rsqrtf(q * (1.f / 128.f) - mean * mean + 1e-5f);
        if ((tid & 15) == 0) { sMean[row] = mean; sRstd[row] = rstd; }
    }
    __syncthreads();
    {   // P4: an2
        short8 wg2[4], ws2[4];
        #pragma unroll
        for (int kk = 0; kk < 4; ++kk) {
            wg2[kk] = WFRAG(Wg2t, 128, n0, kk);
            ws2[kk] = WFRAG(Ws2t, 128, n0, kk);
        }
        #pragma unroll
        for (int mt = 0; mt < 2; ++mt) {
            f32x4 ag = {0.f,0.f,0.f,0.f}, as = {0.f,0.f,0.f,0.f};
            #pragma unroll
            for (int kk = 0; kk < 4; ++kk) {
                short8 a = AFRAG(sSn, 136, mt * 16, kk);
                MFMA(ag, a, wg2[kk]);
                MFMA(as, a, ws2[kk]);
            }
            const int col = n0 + cl;
            float bg2c = bg2[col];
            #pragma unroll
            for (int i = 0; i < 4; ++i) {
                int r = mt * 16 + kg * 4 + i;
                float lnA = (sA[r * 132 + col] - sMean[r]) * sRstd[r];
                sAn2[r * 136 + col] = f2bf(sigmoidf_(ag[i] + bg2c) * lnA + as[i]);
            }
        }
    }
    __syncthreads();
    {   // P5: b = silu(an2@Wsw) * (an2@Wlin)
        short8 a2f[2][4];
        #pragma unroll
        for (int mt = 0; mt < 2; ++mt)
            #pragma unroll
            for (int kk = 0; kk < 4; ++kk)
                a2f[mt][kk] = AFRAG(sAn2, 136, mt * 16, kk);
        #pragma unroll
        for (int j = 0; j < 2; ++j) {
            const int n0b = w * 32 + j * 16;
            short8 ww[4], wl[4];
            #pragma unroll
            for (int kk = 0; kk < 4; ++kk) {
                ww[kk] = WFRAG(Wswt, 128, n0b, kk);
                wl[kk] = WFRAG(Wlint, 128, n0b, kk);
            }
            #pragma unroll
            for (int mt = 0; mt < 2; ++mt) {
                f32x4 aw = {0.f,0.f,0.f,0.f}, al = {0.f,0.f,0.f,0.f};
                #pragma unroll
                for (int kk = 0; kk < 4; ++kk) {
                    MFMA(aw, a2f[mt][kk], ww[kk]);
                    MFMA(al, a2f[mt][kk], wl[kk]);
                }
                const int col2 = n0b + cl;
                #pragma unroll
                for (int i = 0; i < 4; ++i) {
                    int r = mt * 16 + kg * 4 + i;
                    float x = aw[i];
                    float bb = (x / (1.f + expf(-x))) * al[i];
                    sB[r * 264 + col2] = f2bf(bb);
                }
            }
        }
    }
    __syncthreads();
    {   // P6: out = A + g2 * (b @ Wout2)
        short8 wo[8];
        #pragma unroll
        for (int kk = 0; kk < 8; ++kk) wo[kk] = WFRAG(Wout2t, 256, n0, kk);
        #pragma unroll
        for (int mt = 0; mt < 2; ++mt) {
            f32x4 acc = {0.f,0.f,0.f,0.f};
            #pragma unroll
            for (int kk = 0; kk < 8; ++kk) {
                short8 a = AFRAG(sB, 264, mt * 16, kk);
                MFMA(acc, a, wo[kk]);
            }
            const int col = n0 + cl;
            #pragma unroll
            for (int i = 0; i < 4; ++i) {
                int r = mt * 16 + kg * 4 + i;
                long t = t0 + r;
                Out[t * 128 + col] = sA[r * 132 + col] + g2s[mt * 4 + i] * acc[i];
            }
        }
    }
}

// ---------------------------------------------------------------------------
extern "C" void kernel_launch(void* const* d_in, const int* in_sizes, int n_in,
                              void* d_out, int out_size, void* d_ws, size_t ws_size,
                              hipStream_t stream)
{
    const float* A_I  = (const float*)d_in[0];
    const float* S_I  = (const float*)d_in[1];
    const float* Z    = (const float*)d_in[2];
    const float* maskK = (const float*)d_in[6];
    const float* a1Wg = (const float*)d_in[7];
    const float* a1bg = (const float*)d_in[8];
    const float* a1Ws = (const float*)d_in[9];
    const float* Wq   = (const float*)d_in[10];
    const float* bq   = (const float*)d_in[11];
    const float* Wk   = (const float*)d_in[12];
    const float* Wv   = (const float*)d_in[13];
    const float* ln0g = (const float*)d_in[14];
    const float* ln0b = (const float*)d_in[15];
    const float* Wb   = (const float*)d_in[16];
    const float* Wga  = (const float*)d_in[17];
    const float* Wa   = (const float*)d_in[18];
    const float* Wop  = (const float*)d_in[19];
    const float* bop  = (const float*)d_in[20];
    const float* a2Wg = (const float*)d_in[21];
    const float* a2bg = (const float*)d_in[22];
    const float* a2Ws = (const float*)d_in[23];
    const float* Wsw  = (const float*)d_in[24];
    const float* Wlin = (const float*)d_in[25];
    const float* ctWg = (const float*)d_in[26];
    const float* ctbg = (const float*)d_in[27];
    const float* Wout2 = (const float*)d_in[28];
    float* out = (float*)d_out;

    const size_t NTC = (size_t)DL * 128;   // 2,097,152 elems per (D,L,C) tensor
    short* Qb = (short*)d_ws;
    short* Kb = Qb + NTC;
    short* Vb = Kb + NTC;
    short* Gb = Vb + NTC;
    short* BBt = Gb + NTC;                 // [64][4][32][128] bf16 = 2 MB
    short* wbt = BBt + (size_t)NQB * 4 * 32 * 128;
    short* AFb = Qb;   // attention output aliases Qb (Q rows read only by own block)

    short* Wg1t = wbt + 0 * 16384;
    short* Ws1t = wbt + 1 * 16384;
    short* Wqt  = wbt + 2 * 16384;
    short* Wkt  = wbt + 3 * 16384;
    short* Wvt  = wbt + 4 * 16384;
    short* Wgat = wbt + 5 * 16384;
    short* Wat  = wbt + 6 * 16384;
    short* Wopt = wbt + 7 * 16384;
    short* ctWgt = wbt + 8 * 16384;
    short* Wg2t = wbt + 9 * 16384;
    short* Ws2t = wbt + 10 * 16384;
    short* Wswt = wbt + 180224;
    short* Wlint = wbt + 212992;
    short* Wout2t = wbt + 245760;

    k_prep<<<529, 256, 0, stream>>>(a1Wg, a1Ws, Wq, Wk, Wv, Wga, Wa, Wop, ctWg,
                                    a2Wg, a2Ws, Wsw, Wlin, Wout2,
                                    Z, ln0g, ln0b, Wb, wbt, BBt);
    k_adaln_qkvg<<<DL / 32, 512, 0, stream>>>(A_I, S_I, Wg1t, Ws1t, Wqt, Wkt, Wvt, Wgat,
                                              a1bg, bq, Qb, Kb, Vb, Gb);
    k_attn<<<dim3(NQB, 8, 2), 256, 0, stream>>>(Qb, Kb, Vb, Gb, BBt, maskK, AFb);
    k_postf<<<DL / 32, 512, 0, stream>>>(AFb, S_I, A_I, Wat, Wopt, ctWgt, Wg2t, Ws2t,
                                         Wswt, Wlint, Wout2t, bop, ctbg, a2bg, out);
}

// Round 8
// 79.748 us; speedup vs baseline: 1.0282x; 1.0282x over previous
//
#include <hip/hip_runtime.h>

// Problem constants
#define DL 16384   // D*L tokens
#define LL 2048
#define NQB 64     // NQ
#define QBS 32     // QB
#define KBS 128    // KB

typedef __attribute__((ext_vector_type(8))) short short8;
typedef __attribute__((ext_vector_type(4))) short short4v;
typedef __attribute__((ext_vector_type(4))) float f32x4;

__device__ __forceinline__ float sigmoidf_(float x) { return 1.f / (1.f + expf(-x)); }

__device__ __forceinline__ short f2bf(float f) {
    union { float f; unsigned u; } v; v.f = f;
    unsigned r = (v.u + 0x7FFFu + ((v.u >> 16) & 1u)) >> 16;
    return (short)r;
}
__device__ __forceinline__ float bf2f(short h) {
    union { unsigned u; float f; } v; v.u = ((unsigned)(unsigned short)h) << 16;
    return v.f;
}

// fragment helpers (cl = lane&15, kg = lane>>4 must be in scope)
#define AFRAG(buf, stride, r0, kk) (*(const short8*)&(buf)[(size_t)((r0) + cl) * (stride) + (kk) * 32 + kg * 8])
#define WFRAG(Wt, K, n0, kk) (*(const short8*)((Wt) + (size_t)((n0) + cl) * (K) + (kk) * 32 + kg * 8))
#define MFMA(acc, a, b) acc = __builtin_amdgcn_mfma_f32_16x16x32_bf16(a, b, acc, 0, 0, 0)

// ---------------------------------------------------------------------------
// Kernel 0: fused prep.
//   blocks 0..16  : weight transpose to bf16 [N][K] via LDS tile
//   blocks 17..528: pair-bias  BBt[n][h][key:128][q:32] bf16 (4 q-rows/block)
//   Z reads fully coalesced: 4 lanes cooperate per (i,j) pair (64 B row).
// ---------------------------------------------------------------------------
__global__ __launch_bounds__(256) void k_prep(
    const float* __restrict__ W0, const float* __restrict__ W1, const float* __restrict__ W2,
    const float* __restrict__ W3, const float* __restrict__ W4, const float* __restrict__ W5,
    const float* __restrict__ W6, const float* __restrict__ W7, const float* __restrict__ W8,
    const float* __restrict__ W9, const float* __restrict__ W10,
    const float* __restrict__ Wsw, const float* __restrict__ Wlin, const float* __restrict__ Wout2,
    const float* __restrict__ Z, const float* __restrict__ g16, const float* __restrict__ b16,
    const float* __restrict__ Wb,
    short* __restrict__ wout, short* __restrict__ BBt)
{
    __shared__ float sW[128 * 128];          // 64 KB (weight-transpose path)
    __shared__ float sWb[64], sg[16], sb[16];
    __shared__ short sT[4 * 4 * 128];        // bias staging [h][il][j]
    const int b = blockIdx.x;
    const int tid = threadIdx.x;

    if (b < 17) {
        const float* srcs[14] = {W0,W1,W2,W3,W4,W5,W6,W7,W8,W9,W10,Wsw,Wlin,Wout2};
        const int sel[17]  = {0,1,2,3,4,5,6,7,8,9,10,11,11,12,12,13,13};
        const int soff[17] = {0,0,0,0,0,0,0,0,0,0,0, 0,128, 0,128, 0,16384};
        const int sN[17]   = {128,128,128,128,128,128,128,128,128,128,128, 256,256,256,256, 128,128};
        const int doff[17] = {0,16384,32768,49152,65536,81920,98304,114688,131072,147456,163840,
                              180224,196608, 212992,229376, 245760,245888};
        const int dK[17]   = {128,128,128,128,128,128,128,128,128,128,128, 128,128,128,128, 256,256};
        const float* src = srcs[sel[b]] + soff[b];
        const int srcN = sN[b];
        short* dst = wout + doff[b];
        const int dstK = dK[b];
        {   // coalesced load of 128x128 f32 tile
            const int r = tid >> 1, ch = (tid & 1) * 64;
            #pragma unroll
            for (int u = 0; u < 16; ++u) {
                float4 v = *(const float4*)(src + (size_t)r * srcN + ch + u * 4);
                *(float4*)&sW[r * 128 + ch + u * 4] = v;
            }
        }
        __syncthreads();
        {   // coalesced transposed bf16 write
            const int o = tid >> 1, kh = (tid & 1) * 64;
            #pragma unroll
            for (int u8 = 0; u8 < 8; ++u8) {
                short8 pk;
                #pragma unroll
                for (int e = 0; e < 8; ++e)
                    pk[e] = f2bf(sW[(kh + u8 * 8 + e) * 128 + o]);
                *(short8*)(dst + (size_t)o * dstK + kh + u8 * 8) = pk;
            }
        }
    } else {
        const int bb = b - 17;           // 0..511
        const int n = bb >> 3;           // 0..63
        const int io = (bb & 7) * 4;     // 4-row slice
        if (tid < 64) sWb[tid] = Wb[tid];
        if (tid < 16) { sg[tid] = g16[tid]; sb[tid] = b16[tid]; }
        __syncthreads();
        const int q4 = tid & 3;          // cp quarter
        #pragma unroll
        for (int p = 0; p < 8; ++p) {
            int pairIdx = p * 64 + (tid >> 2);   // 0..511
            int il = pairIdx >> 7, j = pairIdx & 127;
            int i = io + il;
            int kr = n * 32 - 48 + j;
            int kc = min(max(kr, 0), LL - 1);
            // 4 lanes read 16B each of the 64B row -> coalesced
            float4 zv = *(const float4*)(Z + ((long)(n * 32 + i) * LL + kc) * 16 + q4 * 4);
            float sm = zv.x + zv.y + zv.z + zv.w;
            float sq = fmaf(zv.x, zv.x, fmaf(zv.y, zv.y, fmaf(zv.z, zv.z, zv.w * zv.w)));
            sm += __shfl_xor(sm, 1); sm += __shfl_xor(sm, 2);
            sq += __shfl_xor(sq, 1); sq += __shfl_xor(sq, 2);
            float m = sm * (1.f / 16.f);
            float rs = rsqrtf(sq * (1.f / 16.f) - m * m + 1e-5f);
            float zn[4];
            zn[0] = (zv.x - m) * rs * sg[q4 * 4 + 0] + sb[q4 * 4 + 0];
            zn[1] = (zv.y - m) * rs * sg[q4 * 4 + 1] + sb[q4 * 4 + 1];
            zn[2] = (zv.z - m) * rs * sg[q4 * 4 + 2] + sb[q4 * 4 + 2];
            zn[3] = (zv.w - m) * rs * sg[q4 * 4 + 3] + sb[q4 * 4 + 3];
            float b0 = 0.f, b1 = 0.f, b2 = 0.f, b3 = 0.f;
            #pragma unroll
            for (int e = 0; e < 4; ++e) {
                int cp = q4 * 4 + e;
                b0 = fmaf(zn[e], sWb[cp * 4 + 0], b0);
                b1 = fmaf(zn[e], sWb[cp * 4 + 1], b1);
                b2 = fmaf(zn[e], sWb[cp * 4 + 2], b2);
                b3 = fmaf(zn[e], sWb[cp * 4 + 3], b3);
            }
            b0 += __shfl_xor(b0, 1); b0 += __shfl_xor(b0, 2);
            b1 += __shfl_xor(b1, 1); b1 += __shfl_xor(b1, 2);
            b2 += __shfl_xor(b2, 1); b2 += __shfl_xor(b2, 2);
            b3 += __shfl_xor(b3, 1); b3 += __shfl_xor(b3, 2);
            float vh = (q4 == 0) ? b0 : (q4 == 1) ? b1 : (q4 == 2) ? b2 : b3;
            sT[(q4 * 4 + il) * 128 + j] = f2bf(vh);
        }
        __syncthreads();
        // write BBt[n][h][key=j][q], q-consecutive (4 rows io..io+3)
        #pragma unroll
        for (int rr = 0; rr < 2; ++rr) {
            int cid = tid + rr * 256;    // 0..511 = h*128 + j
            int hh = cid >> 7, j = cid & 127;
            short4v pk;
            #pragma unroll
            for (int e = 0; e < 4; ++e) pk[e] = sT[(hh * 4 + e) * 128 + j];
            *(short4v*)(BBt + (((size_t)n * 4 + hh) * 128 + j) * 32 + io) = pk;
        }
    }
}

// ---------------------------------------------------------------------------
// Kernel 1: adaLN1 + QKV+G projections via MFMA.
// 32 tokens / block, 512 threads (8 waves): wave w owns col-tile n0=w*16.
// ---------------------------------------------------------------------------
__global__ __launch_bounds__(512) void k_adaln_qkvg(
    const float* __restrict__ A_I, const float* __restrict__ S_I,
    const short* __restrict__ Wg1t, const short* __restrict__ Ws1t,
    const short* __restrict__ Wqt, const short* __restrict__ Wkt,
    const short* __restrict__ Wvt, const short* __restrict__ Wgat,
    const float* __restrict__ bg1, const float* __restrict__ bq,
    short* __restrict__ Qo, short* __restrict__ Ko, short* __restrict__ Vo, short* __restrict__ Go)
{
    __shared__ short sAr[32 * 136];   // raw A bf16
    __shared__ short sSn[32 * 136];   // LN(S) bf16
    __shared__ short sAn[32 * 136];   // An bf16
    __shared__ float sMean[32], sRstd[32];
    const int tid = threadIdx.x;
    const int lane = tid & 63;
    const long t0 = (long)blockIdx.x * 32;

    {   // P0
        const int row = tid >> 4, seg = tid & 15;
        const float* ap = A_I + (t0 + row) * 128 + seg * 8;
        const float* sp = S_I + (t0 + row) * 128 + seg * 8;
        float av[8], sv[8];
        #pragma unroll
        for (int u = 0; u < 2; ++u) {
            float4 a4 = ((const float4*)ap)[u];
            float4 s4 = ((const float4*)sp)[u];
            av[4*u] = a4.x; av[4*u+1] = a4.y; av[4*u+2] = a4.z; av[4*u+3] = a4.w;
            sv[4*u] = s4.x; sv[4*u+1] = s4.y; sv[4*u+2] = s4.z; sv[4*u+3] = s4.w;
        }
        float am = 0.f, aq = 0.f, sm = 0.f, sq = 0.f;
        #pragma unroll
        for (int u = 0; u < 8; ++u) {
            am += av[u]; aq = fmaf(av[u], av[u], aq);
            sm += sv[u]; sq = fmaf(sv[u], sv[u], sq);
        }
        am += __shfl_xor(am, 1); am += __shfl_xor(am, 2); am += __shfl_xor(am, 4); am += __shfl_xor(am, 8);
        aq += __shfl_xor(aq, 1); aq += __shfl_xor(aq, 2); aq += __shfl_xor(aq, 4); aq += __shfl_xor(aq, 8);
        sm += __shfl_xor(sm, 1); sm += __shfl_xor(sm, 2); sm += __shfl_xor(sm, 4); sm += __shfl_xor(sm, 8);
        sq += __shfl_xor(sq, 1); sq += __shfl_xor(sq, 2); sq += __shfl_xor(sq, 4); sq += __shfl_xor(sq, 8);
        float amean = am * (1.f / 128.f);
        float arstd = rsqrtf(aq * (1.f / 128.f) - amean * amean + 1e-5f);
        float smean = sm * (1.f / 128.f);
        float srstd = rsqrtf(sq * (1.f / 128.f) - smean * smean + 1e-5f);
        if ((tid & 15) == 0) { sMean[row] = amean; sRstd[row] = arstd; }
        short8 pa, ps;
        #pragma unroll
        for (int e = 0; e < 8; ++e) {
            pa[e] = f2bf(av[e]);
            ps[e] = f2bf((sv[e] - smean) * srstd);
        }
        *(short8*)&sAr[row * 136 + seg * 8] = pa;
        *(short8*)&sSn[row * 136 + seg * 8] = ps;
    }
    __syncthreads();
    const int w = tid >> 6;
    const int n0 = w * 16;
    const int cl = lane & 15, kg = lane >> 4;
    {   // P1: An
        short8 wg[4], wsf[4];
        #pragma unroll
        for (int kk = 0; kk < 4; ++kk) {
            wg[kk]  = WFRAG(Wg1t, 128, n0, kk);
            wsf[kk] = WFRAG(Ws1t, 128, n0, kk);
        }
        #pragma unroll
        for (int mt = 0; mt < 2; ++mt) {
            f32x4 ag = {0.f, 0.f, 0.f, 0.f}, as = {0.f, 0.f, 0.f, 0.f};
            #pragma unroll
            for (int kk = 0; kk < 4; ++kk) {
                short8 a = AFRAG(sSn, 136, mt * 16, kk);
                MFMA(ag, a, wg[kk]);
                MFMA(as, a, wsf[kk]);
            }
            const int col = n0 + cl;
            float bgc = bg1[col];
            #pragma unroll
            for (int i = 0; i < 4; ++i) {
                int r = mt * 16 + kg * 4 + i;
                float an = (bf2f(sAr[r * 136 + col]) - sMean[r]) * sRstd[r];
                float An = sigmoidf_(ag[i] + bgc) * an + as[i];
                sAn[r * 136 + col] = f2bf(An);
            }
        }
    }
    __syncthreads();
    {   // P2: Q,K,V,G
        const float SCL = 0.17677669529663687f;  // 1/sqrt(32)
        short8 af[2][4];
        #pragma unroll
        for (int mt = 0; mt < 2; ++mt)
            #pragma unroll
            for (int kk = 0; kk < 4; ++kk)
                af[mt][kk] = AFRAG(sAn, 136, mt * 16, kk);
        #pragma unroll
        for (int m = 0; m < 4; ++m) {
            const short* Wt = (m == 0) ? Wqt : (m == 1) ? Wkt : (m == 2) ? Wvt : Wgat;
            short8 wf[4];
            #pragma unroll
            for (int kk = 0; kk < 4; ++kk) wf[kk] = WFRAG(Wt, 128, n0, kk);
            #pragma unroll
            for (int mt = 0; mt < 2; ++mt) {
                f32x4 acc = {0.f, 0.f, 0.f, 0.f};
                #pragma unroll
                for (int kk = 0; kk < 4; ++kk) MFMA(acc, af[mt][kk], wf[kk]);
                const int col = n0 + cl;
                #pragma unroll
                for (int i = 0; i < 4; ++i) {
                    long t = t0 + mt * 16 + kg * 4 + i;
                    float v = acc[i];
                    if (m == 0)      Qo[t * 128 + col] = f2bf((v + bq[col]) * SCL);
                    else if (m == 1) Ko[t * 128 + col] = f2bf(v);
                    else if (m == 2) Vo[t * 128 + col] = f2bf(v);
                    else             Go[t * 128 + col] = f2bf(sigmoidf_(v));
                }
            }
        }
    }
}

// ---------------------------------------------------------------------------
// Kernel 3: windowed attention, block = (n,d), wave = head.  (R6 structure)
// Q/K fragments straight from global; scores in registers; V^T + P in LDS.
// ---------------------------------------------------------------------------
__global__ __launch_bounds__(256) void k_attn(
    const short* __restrict__ Qg, const short* __restrict__ Kg, const short* __restrict__ Vg,
    const short* __restrict__ Gg, const short* __restrict__ BBt, const float* __restrict__ maskK,
    short* __restrict__ AFo)
{
    __shared__ short vts[4 * 32 * 136];   // per-head V^T [c][key]
    __shared__ short Pl [4 * 32 * 136];   // per-head P [q][key]
    const int n = blockIdx.x, d = blockIdx.y;
    const int tid = threadIdx.x;
    const int lane = tid & 63;
    const int h = tid >> 6;
    const long tb = (long)d * LL;
    const int kbase = n * 32 - 48;
    short* vtsH = vts + h * 4352;
    short* PH   = Pl  + h * 4352;
    const int cl = lane & 15, kg = lane >> 4;

    {   // V transpose: lane handles keys 2*lane, 2*lane+1, channels 0..31 of head h
        const int j0 = lane * 2;
        int kc0 = min(max(kbase + j0, 0), LL - 1);
        int kc1 = min(max(kbase + j0 + 1, 0), LL - 1);
        const short8* p0 = (const short8*)(Vg + (tb + kc0) * 128 + h * 32);
        const short8* p1 = (const short8*)(Vg + (tb + kc1) * 128 + h * 32);
        short8 ev[4] = {p0[0], p0[1], p0[2], p0[3]};
        short8 ov[4] = {p1[0], p1[1], p1[2], p1[3]};
        #pragma unroll
        for (int g = 0; g < 4; ++g)
            #pragma unroll
            for (int e = 0; e < 8; ++e)
                *(unsigned*)&vtsH[(g * 8 + e) * 136 + j0] =
                    (unsigned)(unsigned short)ev[g][e] | ((unsigned)(unsigned short)ov[g][e] << 16);
    }
    __syncthreads();

    float sc[2][8][4];
    {   // QK^T straight from global + bias + mask
        short8 qf[2];
        #pragma unroll
        for (int mt = 0; mt < 2; ++mt)
            qf[mt] = *(const short8*)(Qg + (tb + n * 32 + mt * 16 + cl) * 128 + h * 32 + kg * 8);
        #pragma unroll
        for (int nt = 0; nt < 8; ++nt) {
            const int key = nt * 16 + cl;
            int kc = min(max(kbase + key, 0), LL - 1);
            short8 kf = *(const short8*)(Kg + (tb + kc) * 128 + h * 32 + kg * 8);
            float mk = maskK[n * 128 + key] * 1e9f;
            #pragma unroll
            for (int mt = 0; mt < 2; ++mt) {
                f32x4 s = {0.f, 0.f, 0.f, 0.f};
                MFMA(s, qf[mt], kf);
                short4v bfr = *(const short4v*)(BBt + (((size_t)n * 4 + h) * 128 + key) * 32 + mt * 16 + kg * 4);
                #pragma unroll
                for (int i = 0; i < 4; ++i)
                    sc[mt][nt][i] = s[i] + bf2f(bfr[i]) - mk;
            }
        }
    }
    {   // in-register softmax per q-row (16-lane cl-group holds the 128 keys)
        #pragma unroll
        for (int mt = 0; mt < 2; ++mt) {
            #pragma unroll
            for (int i = 0; i < 4; ++i) {
                float mx = sc[mt][0][i];
                #pragma unroll
                for (int nt = 1; nt < 8; ++nt) mx = fmaxf(mx, sc[mt][nt][i]);
                mx = fmaxf(mx, __shfl_xor(mx, 1));
                mx = fmaxf(mx, __shfl_xor(mx, 2));
                mx = fmaxf(mx, __shfl_xor(mx, 4));
                mx = fmaxf(mx, __shfl_xor(mx, 8));
                float sm = 0.f;
                #pragma unroll
                for (int nt = 0; nt < 8; ++nt) {
                    float p = __expf(sc[mt][nt][i] - mx);
                    sc[mt][nt][i] = p; sm += p;
                }
                sm += __shfl_xor(sm, 1);
                sm += __shfl_xor(sm, 2);
                sm += __shfl_xor(sm, 4);
                sm += __shfl_xor(sm, 8);
                float inv = 1.f / sm;
                const int q = mt * 16 + kg * 4 + i;
                #pragma unroll
                for (int nt = 0; nt < 8; ++nt)
                    PH[q * 136 + nt * 16 + cl] = f2bf(sc[mt][nt][i] * inv);
            }
        }
    }
    __syncthreads();
    {   // PV + G-gate + store
        #pragma unroll
        for (int mt = 0; mt < 2; ++mt) {
            #pragma unroll
            for (int ct = 0; ct < 2; ++ct) {
                f32x4 acc = {0.f, 0.f, 0.f, 0.f};
                #pragma unroll
                for (int kk = 0; kk < 4; ++kk) {
                    short8 a = *(const short8*)&PH[(mt * 16 + cl) * 136 + kk * 32 + kg * 8];
                    short8 b = *(const short8*)&vtsH[(ct * 16 + cl) * 136 + kk * 32 + kg * 8];
                    MFMA(acc, a, b);
                }
                const int col = h * 32 + ct * 16 + cl;
                #pragma unroll
                for (int i = 0; i < 4; ++i) {
                    long t = tb + n * 32 + mt * 16 + kg * 4 + i;
                    float g = bf2f(Gg[t * 128 + col]);
                    AFo[t * 128 + col] = f2bf(g * acc[i]);
                }
            }
        }
    }
}

// ---------------------------------------------------------------------------
// Kernel 4: fused post: af@Wa gate residual + adaLN2 + SwiGLU + ct-gate.
// 32 tokens / block, 512 threads (8 waves): wave w owns col-tile n0=w*16.
// ---------------------------------------------------------------------------
__global__ __launch_bounds__(512) void k_postf(
    const short* __restrict__ AF, const float* __restrict__ S_I, const float* __restrict__ A_I,
    const short* __restrict__ Wat, const short* __restrict__ Wopt, const short* __restrict__ ctWgt,
    const short* __restrict__ Wg2t, const short* __restrict__ Ws2t,
    const short* __restrict__ Wswt, const short* __restrict__ Wlint, const short* __restrict__ Wout2t,
    const float* __restrict__ bop, const float* __restrict__ ctbg, const float* __restrict__ bg2,
    float* __restrict__ Out)
{
    __shared__ __align__(16) char smem[43264];
    short* sAF  = (short*)smem;              // [32][136] bf16 AF       -> reused as sAn2
    short* sS   = (short*)(smem + 8704);     // [32][136] bf16 raw S    -> reused by sB
    short* sSn  = (short*)(smem + 17408);    // [32][136] bf16 LN(S)    (partly reused by sB)
    float* sA   = (float*)(smem + 26112);    // [32][132] f32: raw A_I in P0, final A after P2
    float* sMean = (float*)(smem + 43008);   // [32]
    float* sRstd = (float*)(smem + 43136);   // [32]
    short* sAn2 = sAF;                       // [32][136] bf16 an2
    short* sB   = (short*)(smem + 8704);     // [32][264] bf16 b

    const int tid = threadIdx.x;
    const int lane = tid & 63;
    const long t0 = (long)blockIdx.x * 32;

    {   // P0
        const int row = tid >> 4, seg = tid & 15;
        *(short8*)&sAF[row * 136 + seg * 8] =
            *(const short8*)(AF + (t0 + row) * 128 + seg * 8);
        const float* apI = A_I + (t0 + row) * 128 + seg * 8;
        #pragma unroll
        for (int u = 0; u < 2; ++u)
            *(float4*)&sA[row * 132 + seg * 8 + u * 4] = ((const float4*)apI)[u];
        const float* sp = S_I + (t0 + row) * 128 + seg * 8;
        float sv[8];
        #pragma unroll
        for (int u = 0; u < 2; ++u) {
            float4 s4 = ((const float4*)sp)[u];
            sv[4*u] = s4.x; sv[4*u+1] = s4.y; sv[4*u+2] = s4.z; sv[4*u+3] = s4.w;
        }
        float sm = 0.f, sq = 0.f;
        #pragma unroll
        for (int u = 0; u < 8; ++u) { sm += sv[u]; sq = fmaf(sv[u], sv[u], sq); }
        sm += __shfl_xor(sm, 1); sm += __shfl_xor(sm, 2); sm += __shfl_xor(sm, 4); sm += __shfl_xor(sm, 8);
        sq += __shfl_xor(sq, 1); sq += __shfl_xor(sq, 2); sq += __shfl_xor(sq, 4); sq += __shfl_xor(sq, 8);
        float smean = sm * (1.f / 128.f);
        float srstd = rsqrtf(sq * (1.f / 128.f) - smean * smean + 1e-5f);
        short8 pr, pn;
        #pragma unroll
        for (int e = 0; e < 8; ++e) {
            float s = sv[e];
            pr[e] = f2bf(s);
            pn[e] = f2bf((s - smean) * srstd);
        }
        *(short8*)&sS [row * 136 + seg * 8] = pr;
        *(short8*)&sSn[row * 136 + seg * 8] = pn;
    }
    __syncthreads();
    const int w = tid >> 6;
    const int n0 = w * 16;
    const int cl = lane & 15, kg = lane >> 4;
    float g2s[8];

    {   // P2
        short8 wA[4], wO[4], wG[4];
        #pragma unroll
        for (int kk = 0; kk < 4; ++kk) {
            wA[kk] = WFRAG(Wat, 128, n0, kk);
            wO[kk] = WFRAG(Wopt, 128, n0, kk);
            wG[kk] = WFRAG(ctWgt, 128, n0, kk);
        }
        #pragma unroll
        for (int mt = 0; mt < 2; ++mt) {
            f32x4 aA = {0.f,0.f,0.f,0.f}, aO = {0.f,0.f,0.f,0.f}, aG = {0.f,0.f,0.f,0.f};
            #pragma unroll
            for (int kk = 0; kk < 4; ++kk) {
                short8 af = AFRAG(sAF, 136, mt * 16, kk);
                short8 sf = AFRAG(sS, 136, mt * 16, kk);
                MFMA(aA, af, wA[kk]);
                MFMA(aO, sf, wO[kk]);
                MFMA(aG, sf, wG[kk]);
            }
            const int col = n0 + cl;
            float bopc = bop[col], ctc = ctbg[col];
            #pragma unroll
            for (int i = 0; i < 4; ++i) {
                int r = mt * 16 + kg * 4 + i;
                float Aval = sA[r * 132 + col] + sigmoidf_(aO[i] + bopc) * aA[i];
                sA[r * 132 + col] = Aval;
                g2s[mt * 4 + i] = sigmoidf_(aG[i] + ctc);
            }
        }
    }
    __syncthreads();
    {   // P3: LN stats of A rows
        const int row = tid >> 4, seg = tid & 15;
        float m = 0.f, q = 0.f;
        #pragma unroll
        for (int u = 0; u < 2; ++u) {
            float4 v = *(const float4*)&sA[row * 132 + seg * 8 + u * 4];
            m += v.x + v.y + v.z + v.w;
            q = fmaf(v.x, v.x, q); q = fmaf(v.y, v.y, q);
            q = fmaf(v.z, v.z, q); q = fmaf(v.w, v.w, q);
        }
        m += __shfl_xor(m, 1); m += __shfl_xor(m, 2); m += __shfl_xor(m, 4); m += __shfl_xor(m, 8);
        q += __shfl_xor(q, 1); q += __shfl_xor(q, 2); q += __shfl_xor(q, 4); q += __shfl_xor(q, 8);
        float mean = m * (1.f / 128.f);
        float rstd = rsqrtf(q * (1.f / 128.f) - mean * mean + 1e-5f);
        if ((tid & 15) == 0) { sMean[row] = mean; sRstd[row] = rstd; }
    }
    __syncthreads();
    {   // P4: an2
        short8 wg2[4], ws2[4];
        #pragma unroll
        for (int kk = 0; kk < 4; ++kk) {
            wg2[kk] = WFRAG(Wg2t, 128, n0, kk);
            ws2[kk] = WFRAG(Ws2t, 128, n0, kk);
        }
        #pragma unroll
        for (int mt = 0; mt < 2; ++mt) {
            f32x4 ag = {0.f,0.f,0.f,0.f}, as = {0.f,0.f,0.f,0.f};
            #pragma unroll
            for (int kk = 0; kk < 4; ++kk) {
                short8 a = AFRAG(sSn, 136, mt * 16, kk);
                MFMA(ag, a, wg2[kk]);
                MFMA(as, a, ws2[kk]);
            }
            const int col = n0 + cl;
            float bg2c = bg2[col];
            #pragma unroll
            for (int i = 0; i < 4; ++i) {
                int r = mt * 16 + kg * 4 + i;
                float lnA = (sA[r * 132 + col] - sMean[r]) * sRstd[r];
                sAn2[r * 136 + col] = f2bf(sigmoidf_(ag[i] + bg2c) * lnA + as[i]);
            }
        }
    }
    __syncthreads();
    {   // P5: b = silu(an2@Wsw) * (an2@Wlin)
        short8 a2f[2][4];
        #pragma unroll
        for (int mt = 0; mt < 2; ++mt)
            #pragma unroll
            for (int kk = 0; kk < 4; ++kk)
                a2f[mt][kk] = AFRAG(sAn2, 136, mt * 16, kk);
        #pragma unroll
        for (int j = 0; j < 2; ++j) {
            const int n0b = w * 32 + j * 16;
            short8 ww[4], wl[4];
            #pragma unroll
            for (int kk = 0; kk < 4; ++kk) {
                ww[kk] = WFRAG(Wswt, 128, n0b, kk);
                wl[kk] = WFRAG(Wlint, 128, n0b, kk);
            }
            #pragma unroll
            for (int mt = 0; mt < 2; ++mt) {
                f32x4 aw = {0.f,0.f,0.f,0.f}, al = {0.f,0.f,0.f,0.f};
                #pragma unroll
                for (int kk = 0; kk < 4; ++kk) {
                    MFMA(aw, a2f[mt][kk], ww[kk]);
                    MFMA(al, a2f[mt][kk], wl[kk]);
                }
                const int col2 = n0b + cl;
                #pragma unroll
                for (int i = 0; i < 4; ++i) {
                    int r = mt * 16 + kg * 4 + i;
                    float x = aw[i];
                    float bb = (x / (1.f + expf(-x))) * al[i];
                    sB[r * 264 + col2] = f2bf(bb);
                }
            }
        }
    }
    __syncthreads();
    {   // P6: out = A + g2 * (b @ Wout2)
        short8 wo[8];
        #pragma unroll
        for (int kk = 0; kk < 8; ++kk) wo[kk] = WFRAG(Wout2t, 256, n0, kk);
        #pragma unroll
        for (int mt = 0; mt < 2; ++mt) {
            f32x4 acc = {0.f,0.f,0.f,0.f};
            #pragma unroll
            for (int kk = 0; kk < 8; ++kk) {
                short8 a = AFRAG(sB, 264, mt * 16, kk);
                MFMA(acc, a, wo[kk]);
            }
            const int col = n0 + cl;
            #pragma unroll
            for (int i = 0; i < 4; ++i) {
                int r = mt * 16 + kg * 4 + i;
                long t = t0 + r;
                Out[t * 128 + col] = sA[r * 132 + col] + g2s[mt * 4 + i] * acc[i];
            }
        }
    }
}

// ---------------------------------------------------------------------------
extern "C" void kernel_launch(void* const* d_in, const int* in_sizes, int n_in,
                              void* d_out, int out_size, void* d_ws, size_t ws_size,
                              hipStream_t stream)
{
    const float* A_I  = (const float*)d_in[0];
    const float* S_I  = (const float*)d_in[1];
    const float* Z    = (const float*)d_in[2];
    const float* maskK = (const float*)d_in[6];
    const float* a1Wg = (const float*)d_in[7];
    const float* a1bg = (const float*)d_in[8];
    const float* a1Ws = (const float*)d_in[9];
    const float* Wq   = (const float*)d_in[10];
    const float* bq   = (const float*)d_in[11];
    const float* Wk   = (const float*)d_in[12];
    const float* Wv   = (const float*)d_in[13];
    const float* ln0g = (const float*)d_in[14];
    const float* ln0b = (const float*)d_in[15];
    const float* Wb   = (const float*)d_in[16];
    const float* Wga  = (const float*)d_in[17];
    const float* Wa   = (const float*)d_in[18];
    const float* Wop  = (const float*)d_in[19];
    const float* bop  = (const float*)d_in[20];
    const float* a2Wg = (const float*)d_in[21];
    const float* a2bg = (const float*)d_in[22];
    const float* a2Ws = (const float*)d_in[23];
    const float* Wsw  = (const float*)d_in[24];
    const float* Wlin = (const float*)d_in[25];
    const float* ctWg = (const float*)d_in[26];
    const float* ctbg = (const float*)d_in[27];
    const float* Wout2 = (const float*)d_in[28];
    float* out = (float*)d_out;

    const size_t NTC = (size_t)DL * 128;   // 2,097,152 elems per (D,L,C) tensor
    short* Qb = (short*)d_ws;
    short* Kb = Qb + NTC;
    short* Vb = Kb + NTC;
    short* Gb = Vb + NTC;
    short* BBt = Gb + NTC;                 // [64][4][128][32] bf16 = 2 MB
    short* wbt = BBt + (size_t)NQB * 4 * 128 * 32;
    short* AFb = Qb;   // attention output aliases Qb (block-local RAW, barrier-separated)

    short* Wg1t = wbt + 0 * 16384;
    short* Ws1t = wbt + 1 * 16384;
    short* Wqt  = wbt + 2 * 16384;
    short* Wkt  = wbt + 3 * 16384;
    short* Wvt  = wbt + 4 * 16384;
    short* Wgat = wbt + 5 * 16384;
    short* Wat  = wbt + 6 * 16384;
    short* Wopt = wbt + 7 * 16384;
    short* ctWgt = wbt + 8 * 16384;
    short* Wg2t = wbt + 9 * 16384;
    short* Ws2t = wbt + 10 * 16384;
    short* Wswt = wbt + 180224;
    short* Wlint = wbt + 212992;
    short* Wout2t = wbt + 245760;

    k_prep<<<529, 256, 0, stream>>>(a1Wg, a1Ws, Wq, Wk, Wv, Wga, Wa, Wop, ctWg,
                                    a2Wg, a2Ws, Wsw, Wlin, Wout2,
                                    Z, ln0g, ln0b, Wb, wbt, BBt);
    k_adaln_qkvg<<<DL / 32, 512, 0, stream>>>(A_I, S_I, Wg1t, Ws1t, Wqt, Wkt, Wvt, Wgat,
                                              a1bg, bq, Qb, Kb, Vb, Gb);
    k_attn<<<dim3(NQB, 8), 256, 0, stream>>>(Qb, Kb, Vb, Gb, BBt, maskK, AFb);
    k_postf<<<DL / 32, 512, 0, stream>>>(AFb, S_I, A_I, Wat, Wopt, ctWgt, Wg2t, Ws2t,
                                         Wswt, Wlint, Wout2t, bop, ctbg, a2bg, out);
}

// Round 9
// 70.353 us; speedup vs baseline: 1.1655x; 1.1335x over previous
//
#include <hip/hip_runtime.h>

// Problem constants
#define DL 16384   // D*L tokens
#define LL 2048
#define NQB 64     // NQ
#define QBS 32     // QB
#define KBS 128    // KB

typedef __attribute__((ext_vector_type(8))) short short8;
typedef __attribute__((ext_vector_type(4))) short short4v;
typedef __attribute__((ext_vector_type(4))) float f32x4;

__device__ __forceinline__ float sigmoidf_(float x) { return 1.f / (1.f + expf(-x)); }

__device__ __forceinline__ short f2bf(float f) {
    union { float f; unsigned u; } v; v.f = f;
    unsigned r = (v.u + 0x7FFFu + ((v.u >> 16) & 1u)) >> 16;
    return (short)r;
}
__device__ __forceinline__ unsigned f2bfu(float f) {
    union { float f; unsigned u; } v; v.f = f;
    return (v.u + 0x7FFFu + ((v.u >> 16) & 1u)) >> 16;
}
__device__ __forceinline__ float bf2f(short h) {
    union { unsigned u; float f; } v; v.u = ((unsigned)(unsigned short)h) << 16;
    return v.f;
}
__device__ __forceinline__ unsigned packbf16(short a, short b) {
    return ((unsigned)(unsigned short)a) | (((unsigned)(unsigned short)b) << 16);
}

// fragment helpers (cl = lane&15, kg = lane>>4 must be in scope)
#define AFRAG(buf, stride, r0, kk) (*(const short8*)&(buf)[(size_t)((r0) + cl) * (stride) + (kk) * 32 + kg * 8])
#define WFRAG(Wt, K, n0, kk) (*(const short8*)((Wt) + (size_t)((n0) + cl) * (K) + (kk) * 32 + kg * 8))
#define MFMA(acc, a, b) acc = __builtin_amdgcn_mfma_f32_16x16x32_bf16(a, b, acc, 0, 0, 0)

// ---------------------------------------------------------------------------
// Kernel 0: fused prep (R6-validated version).
//   blocks 0..16  : weight transpose to bf16 [N][K] via LDS tile
//   blocks 17..528: pair-bias  BBt[n][h][key:128][q:32] bf16 (4 q-rows/block)
// ---------------------------------------------------------------------------
__global__ __launch_bounds__(256) void k_prep(
    const float* __restrict__ W0, const float* __restrict__ W1, const float* __restrict__ W2,
    const float* __restrict__ W3, const float* __restrict__ W4, const float* __restrict__ W5,
    const float* __restrict__ W6, const float* __restrict__ W7, const float* __restrict__ W8,
    const float* __restrict__ W9, const float* __restrict__ W10,
    const float* __restrict__ Wsw, const float* __restrict__ Wlin, const float* __restrict__ Wout2,
    const float* __restrict__ Z, const float* __restrict__ g16, const float* __restrict__ b16,
    const float* __restrict__ Wb,
    short* __restrict__ wout, short* __restrict__ BBt)
{
    __shared__ float sW[128 * 128];          // 64 KB (weight-transpose path)
    __shared__ float sWb[64], sg[16], sb[16];
    __shared__ short sT[4 * 4 * 128];        // bias staging [h][il][j]
    const int b = blockIdx.x;
    const int tid = threadIdx.x;

    if (b < 17) {
        const float* srcs[14] = {W0,W1,W2,W3,W4,W5,W6,W7,W8,W9,W10,Wsw,Wlin,Wout2};
        const int sel[17]  = {0,1,2,3,4,5,6,7,8,9,10,11,11,12,12,13,13};
        const int soff[17] = {0,0,0,0,0,0,0,0,0,0,0, 0,128, 0,128, 0,16384};
        const int sN[17]   = {128,128,128,128,128,128,128,128,128,128,128, 256,256,256,256, 128,128};
        const int doff[17] = {0,16384,32768,49152,65536,81920,98304,114688,131072,147456,163840,
                              180224,196608, 212992,229376, 245760,245888};
        const int dK[17]   = {128,128,128,128,128,128,128,128,128,128,128, 128,128,128,128, 256,256};
        const float* src = srcs[sel[b]] + soff[b];
        const int srcN = sN[b];
        short* dst = wout + doff[b];
        const int dstK = dK[b];
        {   // coalesced load of 128x128 f32 tile
            const int r = tid >> 1, ch = (tid & 1) * 64;
            #pragma unroll
            for (int u = 0; u < 16; ++u) {
                float4 v = *(const float4*)(src + (size_t)r * srcN + ch + u * 4);
                *(float4*)&sW[r * 128 + ch + u * 4] = v;
            }
        }
        __syncthreads();
        {   // coalesced transposed bf16 write
            const int o = tid >> 1, kh = (tid & 1) * 64;
            #pragma unroll
            for (int u8 = 0; u8 < 8; ++u8) {
                short8 pk;
                #pragma unroll
                for (int e = 0; e < 8; ++e)
                    pk[e] = f2bf(sW[(kh + u8 * 8 + e) * 128 + o]);
                *(short8*)(dst + (size_t)o * dstK + kh + u8 * 8) = pk;
            }
        }
    } else {
        const int bb = b - 17;           // 0..511
        const int n = bb >> 3;           // 0..63
        const int io = (bb & 7) * 4;     // 4-row slice
        if (tid < 64) sWb[tid] = Wb[tid];
        if (tid < 16) { sg[tid] = g16[tid]; sb[tid] = b16[tid]; }
        __syncthreads();
        #pragma unroll
        for (int p = 0; p < 2; ++p) {
            int pair = tid + 256 * p;        // 4*128 pairs
            int il = pair >> 7, j = pair & 127;
            int i = io + il;
            int kr = n * 32 - 48 + j;
            int kc = min(max(kr, 0), LL - 1);
            const float4* z4 = (const float4*)(Z + ((long)(n * 32 + i) * LL + kc) * 16);
            float zv[16];
            #pragma unroll
            for (int w = 0; w < 4; ++w) {
                float4 v = z4[w];
                zv[w * 4 + 0] = v.x; zv[w * 4 + 1] = v.y; zv[w * 4 + 2] = v.z; zv[w * 4 + 3] = v.w;
            }
            float sm = 0.f, sq = 0.f;
            #pragma unroll
            for (int cp = 0; cp < 16; ++cp) { sm += zv[cp]; sq = fmaf(zv[cp], zv[cp], sq); }
            float m = sm * (1.f / 16.f);
            float rs = rsqrtf(sq * (1.f / 16.f) - m * m + 1e-5f);
            float b0 = 0.f, b1 = 0.f, b2 = 0.f, b3 = 0.f;
            #pragma unroll
            for (int cp = 0; cp < 16; ++cp) {
                float zn = (zv[cp] - m) * rs * sg[cp] + sb[cp];
                b0 = fmaf(zn, sWb[cp * 4 + 0], b0);
                b1 = fmaf(zn, sWb[cp * 4 + 1], b1);
                b2 = fmaf(zn, sWb[cp * 4 + 2], b2);
                b3 = fmaf(zn, sWb[cp * 4 + 3], b3);
            }
            sT[(0 * 4 + il) * 128 + j] = f2bf(b0);
            sT[(1 * 4 + il) * 128 + j] = f2bf(b1);
            sT[(2 * 4 + il) * 128 + j] = f2bf(b2);
            sT[(3 * 4 + il) * 128 + j] = f2bf(b3);
        }
        __syncthreads();
        // write BBt[n][h][key=j][q], q-consecutive (4 rows io..io+3)
        #pragma unroll
        for (int rr = 0; rr < 2; ++rr) {
            int cid = tid + rr * 256;    // 0..511 = h*128 + j
            int hh = cid >> 7, j = cid & 127;
            short4v pk;
            #pragma unroll
            for (int e = 0; e < 4; ++e) pk[e] = sT[(hh * 4 + e) * 128 + j];
            *(short4v*)(BBt + (((size_t)n * 4 + hh) * 128 + j) * 32 + io) = pk;
        }
    }
}

// ---------------------------------------------------------------------------
// Kernel 1: adaLN1 + QKV+G projections via MFMA.
// 32 tokens / block, 512 threads (8 waves): wave w owns col-tile n0=w*16.
// ---------------------------------------------------------------------------
__global__ __launch_bounds__(512) void k_adaln_qkvg(
    const float* __restrict__ A_I, const float* __restrict__ S_I,
    const short* __restrict__ Wg1t, const short* __restrict__ Ws1t,
    const short* __restrict__ Wqt, const short* __restrict__ Wkt,
    const short* __restrict__ Wvt, const short* __restrict__ Wgat,
    const float* __restrict__ bg1, const float* __restrict__ bq,
    short* __restrict__ Qo, short* __restrict__ Ko, short* __restrict__ Vo, short* __restrict__ Go)
{
    __shared__ short sAr[32 * 136];   // raw A bf16
    __shared__ short sSn[32 * 136];   // LN(S) bf16
    __shared__ short sAn[32 * 136];   // An bf16
    __shared__ float sMean[32], sRstd[32];
    const int tid = threadIdx.x;
    const int lane = tid & 63;
    const long t0 = (long)blockIdx.x * 32;

    {   // P0
        const int row = tid >> 4, seg = tid & 15;
        const float* ap = A_I + (t0 + row) * 128 + seg * 8;
        const float* sp = S_I + (t0 + row) * 128 + seg * 8;
        float av[8], sv[8];
        #pragma unroll
        for (int u = 0; u < 2; ++u) {
            float4 a4 = ((const float4*)ap)[u];
            float4 s4 = ((const float4*)sp)[u];
            av[4*u] = a4.x; av[4*u+1] = a4.y; av[4*u+2] = a4.z; av[4*u+3] = a4.w;
            sv[4*u] = s4.x; sv[4*u+1] = s4.y; sv[4*u+2] = s4.z; sv[4*u+3] = s4.w;
        }
        float am = 0.f, aq = 0.f, sm = 0.f, sq = 0.f;
        #pragma unroll
        for (int u = 0; u < 8; ++u) {
            am += av[u]; aq = fmaf(av[u], av[u], aq);
            sm += sv[u]; sq = fmaf(sv[u], sv[u], sq);
        }
        am += __shfl_xor(am, 1); am += __shfl_xor(am, 2); am += __shfl_xor(am, 4); am += __shfl_xor(am, 8);
        aq += __shfl_xor(aq, 1); aq += __shfl_xor(aq, 2); aq += __shfl_xor(aq, 4); aq += __shfl_xor(aq, 8);
        sm += __shfl_xor(sm, 1); sm += __shfl_xor(sm, 2); sm += __shfl_xor(sm, 4); sm += __shfl_xor(sm, 8);
        sq += __shfl_xor(sq, 1); sq += __shfl_xor(sq, 2); sq += __shfl_xor(sq, 4); sq += __shfl_xor(sq, 8);
        float amean = am * (1.f / 128.f);
        float arstd = rsqrtf(aq * (1.f / 128.f) - amean * amean + 1e-5f);
        float smean = sm * (1.f / 128.f);
        float srstd = rsqrtf(sq * (1.f / 128.f) - smean * smean + 1e-5f);
        if ((tid & 15) == 0) { sMean[row] = amean; sRstd[row] = arstd; }
        short8 pa, ps;
        #pragma unroll
        for (int e = 0; e < 8; ++e) {
            pa[e] = f2bf(av[e]);
            ps[e] = f2bf((sv[e] - smean) * srstd);
        }
        *(short8*)&sAr[row * 136 + seg * 8] = pa;
        *(short8*)&sSn[row * 136 + seg * 8] = ps;
    }
    __syncthreads();
    const int w = tid >> 6;
    const int n0 = w * 16;
    const int cl = lane & 15, kg = lane >> 4;
    {   // P1: An
        short8 wg[4], wsf[4];
        #pragma unroll
        for (int kk = 0; kk < 4; ++kk) {
            wg[kk]  = WFRAG(Wg1t, 128, n0, kk);
            wsf[kk] = WFRAG(Ws1t, 128, n0, kk);
        }
        #pragma unroll
        for (int mt = 0; mt < 2; ++mt) {
            f32x4 ag = {0.f, 0.f, 0.f, 0.f}, as = {0.f, 0.f, 0.f, 0.f};
            #pragma unroll
            for (int kk = 0; kk < 4; ++kk) {
                short8 a = AFRAG(sSn, 136, mt * 16, kk);
                MFMA(ag, a, wg[kk]);
                MFMA(as, a, wsf[kk]);
            }
            const int col = n0 + cl;
            float bgc = bg1[col];
            #pragma unroll
            for (int i = 0; i < 4; ++i) {
                int r = mt * 16 + kg * 4 + i;
                float an = (bf2f(sAr[r * 136 + col]) - sMean[r]) * sRstd[r];
                float An = sigmoidf_(ag[i] + bgc) * an + as[i];
                sAn[r * 136 + col] = f2bf(An);
            }
        }
    }
    __syncthreads();
    {   // P2: Q,K,V,G
        const float SCL = 0.17677669529663687f;  // 1/sqrt(32)
        short8 af[2][4];
        #pragma unroll
        for (int mt = 0; mt < 2; ++mt)
            #pragma unroll
            for (int kk = 0; kk < 4; ++kk)
                af[mt][kk] = AFRAG(sAn, 136, mt * 16, kk);
        #pragma unroll
        for (int m = 0; m < 4; ++m) {
            const short* Wt = (m == 0) ? Wqt : (m == 1) ? Wkt : (m == 2) ? Wvt : Wgat;
            short8 wf[4];
            #pragma unroll
            for (int kk = 0; kk < 4; ++kk) wf[kk] = WFRAG(Wt, 128, n0, kk);
            #pragma unroll
            for (int mt = 0; mt < 2; ++mt) {
                f32x4 acc = {0.f, 0.f, 0.f, 0.f};
                #pragma unroll
                for (int kk = 0; kk < 4; ++kk) MFMA(acc, af[mt][kk], wf[kk]);
                const int col = n0 + cl;
                #pragma unroll
                for (int i = 0; i < 4; ++i) {
                    long t = t0 + mt * 16 + kg * 4 + i;
                    float v = acc[i];
                    if (m == 0)      Qo[t * 128 + col] = f2bf((v + bq[col]) * SCL);
                    else if (m == 1) Ko[t * 128 + col] = f2bf(v);
                    else if (m == 2) Vo[t * 128 + col] = f2bf(v);
                    else             Go[t * 128 + col] = f2bf(sigmoidf_(v));
                }
            }
        }
    }
}

// ---------------------------------------------------------------------------
// Kernel 2: FUSED attention + post.  Block (n,d) == postf block for tokens
// t0 = d*2048 + n*32.  512 threads.  Attention: wave = (head, q-half);
// AF passes through LDS (no global round-trip).
// ---------------------------------------------------------------------------
__global__ __launch_bounds__(512) void k_attn_postf(
    const short* __restrict__ Qg, const short* __restrict__ Kg, const short* __restrict__ Vg,
    const short* __restrict__ Gg, const short* __restrict__ BBt, const float* __restrict__ maskK,
    const float* __restrict__ S_I, const float* __restrict__ A_I,
    const short* __restrict__ Wat, const short* __restrict__ Wopt, const short* __restrict__ ctWgt,
    const short* __restrict__ Wg2t, const short* __restrict__ Ws2t,
    const short* __restrict__ Wswt, const short* __restrict__ Wlint, const short* __restrict__ Wout2t,
    const float* __restrict__ bop, const float* __restrict__ ctbg, const float* __restrict__ bg2,
    float* __restrict__ Out)
{
    __shared__ __align__(16) char smem[78336];
    short* sAF  = (short*)smem;              // [32][136] attn-out bf16 -> later an2
    short* vts  = (short*)(smem + 8704);     // [4][32][136] V^T   (attn phase)
    short* Pl   = (short*)(smem + 43520);    // [4][32][136] P     (attn phase)
    // post phase (overlays vts/Pl after barrier):
    short* sS   = (short*)(smem + 8704);     // [32][136] raw S bf16 -> sB
    short* sSn  = (short*)(smem + 17408);    // [32][136] LN(S) bf16
    float* sA   = (float*)(smem + 26112);    // [32][132] f32 A
    float* sMean = (float*)(smem + 43008);   // [32]
    float* sRstd = (float*)(smem + 43136);   // [32]
    short* sAn2 = sAF;
    short* sB   = (short*)(smem + 8704);     // [32][264] bf16 b

    const int n = blockIdx.x, d = blockIdx.y;
    const int tid = threadIdx.x;
    const int lane = tid & 63;
    const long tb = (long)d * LL;
    const long t0 = tb + n * 32;
    const int kbase = n * 32 - 48;
    const int cl = lane & 15, kg = lane >> 4;
    const int w = tid >> 6;
    const int h = w >> 1, amt = w & 1;       // attn wave = (head, q-half)

    {   // V^T staging: 512 threads; unit=(head,key-pair), half=16-channel half
        const int unit = tid >> 1, half = tid & 1;
        const int hh = unit >> 6, j0 = (unit & 63) * 2;
        int kc0 = min(max(kbase + j0, 0), LL - 1);
        int kc1 = min(max(kbase + j0 + 1, 0), LL - 1);
        const short8* p0 = (const short8*)(Vg + (tb + kc0) * 128 + hh * 32 + half * 16);
        const short8* p1 = (const short8*)(Vg + (tb + kc1) * 128 + hh * 32 + half * 16);
        short8 e0 = p0[0], e1 = p0[1];
        short8 o0 = p1[0], o1 = p1[1];
        short* vh = vts + hh * 4352;
        #pragma unroll
        for (int e = 0; e < 8; ++e)
            *(unsigned*)&vh[(half * 16 + e) * 136 + j0] = packbf16(e0[e], o0[e]);
        #pragma unroll
        for (int e = 0; e < 8; ++e)
            *(unsigned*)&vh[(half * 16 + 8 + e) * 136 + j0] = packbf16(e1[e], o1[e]);
    }

    float sc[8][4];
    {   // QK^T straight from global + bias + mask (wave handles q-half amt)
        short8 qf = *(const short8*)(Qg + (t0 + amt * 16 + cl) * 128 + h * 32 + kg * 8);
        #pragma unroll
        for (int nt = 0; nt < 8; ++nt) {
            const int key = nt * 16 + cl;
            int kc = min(max(kbase + key, 0), LL - 1);
            short8 kf = *(const short8*)(Kg + (tb + kc) * 128 + h * 32 + kg * 8);
            float mk = maskK[n * 128 + key] * 1e9f;
            f32x4 s = {0.f, 0.f, 0.f, 0.f};
            MFMA(s, qf, kf);
            short4v bfr = *(const short4v*)(BBt + (((size_t)n * 4 + h) * 128 + key) * 32 + amt * 16 + kg * 4);
            #pragma unroll
            for (int i = 0; i < 4; ++i)
                sc[nt][i] = s[i] + bf2f(bfr[i]) - mk;
        }
    }
    {   // softmax per q-row (reduce across 16-lane cl group), write P to LDS
        short* PH = Pl + h * 4352;
        #pragma unroll
        for (int i = 0; i < 4; ++i) {
            float mx = sc[0][i];
            #pragma unroll
            for (int nt = 1; nt < 8; ++nt) mx = fmaxf(mx, sc[nt][i]);
            mx = fmaxf(mx, __shfl_xor(mx, 1));
            mx = fmaxf(mx, __shfl_xor(mx, 2));
            mx = fmaxf(mx, __shfl_xor(mx, 4));
            mx = fmaxf(mx, __shfl_xor(mx, 8));
            float sm = 0.f;
            #pragma unroll
            for (int nt = 0; nt < 8; ++nt) {
                float p = __expf(sc[nt][i] - mx);
                sc[nt][i] = p; sm += p;
            }
            sm += __shfl_xor(sm, 1);
            sm += __shfl_xor(sm, 2);
            sm += __shfl_xor(sm, 4);
            sm += __shfl_xor(sm, 8);
            float inv = 1.f / sm;
            const int q = amt * 16 + kg * 4 + i;
            #pragma unroll
            for (int nt = 0; nt < 8; ++nt)
                PH[q * 136 + nt * 16 + cl] = f2bf(sc[nt][i] * inv);
        }
    }
    __syncthreads();   // V^T + P complete
    {   // PV + G-gate -> sAF (LDS)
        short* PH = Pl + h * 4352;
        short* vh = vts + h * 4352;
        #pragma unroll
        for (int ct = 0; ct < 2; ++ct) {
            f32x4 acc = {0.f, 0.f, 0.f, 0.f};
            #pragma unroll
            for (int kk = 0; kk < 4; ++kk) {
                short8 a = *(const short8*)&PH[(amt * 16 + cl) * 136 + kk * 32 + kg * 8];
                short8 b = *(const short8*)&vh[(ct * 16 + cl) * 136 + kk * 32 + kg * 8];
                MFMA(acc, a, b);
            }
            const int col = h * 32 + ct * 16 + cl;
            #pragma unroll
            for (int i = 0; i < 4; ++i) {
                int r = amt * 16 + kg * 4 + i;
                float g = bf2f(Gg[(t0 + r) * 128 + col]);
                sAF[r * 136 + col] = f2bf(g * acc[i]);
            }
        }
    }
    __syncthreads();   // attn done; vts/Pl now dead

    // ---------------- post phase ----------------
    {   // P0: load A_I -> sA f32; S -> raw bf16 + LN bf16 (overlays vts/Pl)
        const int row = tid >> 4, seg = tid & 15;
        const float* apI = A_I + (t0 + row) * 128 + seg * 8;
        #pragma unroll
        for (int u = 0; u < 2; ++u)
            *(float4*)&sA[row * 132 + seg * 8 + u * 4] = ((const float4*)apI)[u];
        const float* sp = S_I + (t0 + row) * 128 + seg * 8;
        float sv[8];
        #pragma unroll
        for (int u = 0; u < 2; ++u) {
            float4 s4 = ((const float4*)sp)[u];
            sv[4*u] = s4.x; sv[4*u+1] = s4.y; sv[4*u+2] = s4.z; sv[4*u+3] = s4.w;
        }
        float sm = 0.f, sq = 0.f;
        #pragma unroll
        for (int u = 0; u < 8; ++u) { sm += sv[u]; sq = fmaf(sv[u], sv[u], sq); }
        sm += __shfl_xor(sm, 1); sm += __shfl_xor(sm, 2); sm += __shfl_xor(sm, 4); sm += __shfl_xor(sm, 8);
        sq += __shfl_xor(sq, 1); sq += __shfl_xor(sq, 2); sq += __shfl_xor(sq, 4); sq += __shfl_xor(sq, 8);
        float smean = sm * (1.f / 128.f);
        float srstd = rsqrtf(sq * (1.f / 128.f) - smean * smean + 1e-5f);
        short8 pr, pn;
        #pragma unroll
        for (int e = 0; e < 8; ++e) {
            float s = sv[e];
            pr[e] = f2bf(s);
            pn[e] = f2bf((s - smean) * srstd);
        }
        *(short8*)&sS [row * 136 + seg * 8] = pr;
        *(short8*)&sSn[row * 136 + seg * 8] = pn;
    }
    __syncthreads();
    const int n0 = w * 16;
    float g2s[8];

    {   // P2: A = A_I + sigmoid(S@Wop+bop)*(AF@Wa);  g2 = sigmoid(S@ctWg+ctbg)
        short8 wA[4], wO[4], wG[4];
        #pragma unroll
        for (int kk = 0; kk < 4; ++kk) {
            wA[kk] = WFRAG(Wat, 128, n0, kk);
            wO[kk] = WFRAG(Wopt, 128, n0, kk);
            wG[kk] = WFRAG(ctWgt, 128, n0, kk);
        }
        #pragma unroll
        for (int rt = 0; rt < 2; ++rt) {
            f32x4 aA = {0.f,0.f,0.f,0.f}, aO = {0.f,0.f,0.f,0.f}, aG = {0.f,0.f,0.f,0.f};
            #pragma unroll
            for (int kk = 0; kk < 4; ++kk) {
                short8 af = AFRAG(sAF, 136, rt * 16, kk);
                short8 sf = AFRAG(sS, 136, rt * 16, kk);
                MFMA(aA, af, wA[kk]);
                MFMA(aO, sf, wO[kk]);
                MFMA(aG, sf, wG[kk]);
            }
            const int col = n0 + cl;
            float bopc = bop[col], ctc = ctbg[col];
            #pragma unroll
            for (int i = 0; i < 4; ++i) {
                int r = rt * 16 + kg * 4 + i;
                float Aval = sA[r * 132 + col] + sigmoidf_(aO[i] + bopc) * aA[i];
                sA[r * 132 + col] = Aval;
                g2s[rt * 4 + i] = sigmoidf_(aG[i] + ctc);
            }
        }
    }
    __syncthreads();
    {   // P3: LN stats of A rows
        const int row = tid >> 4, seg = tid & 15;
        float m = 0.f, q = 0.f;
        #pragma unroll
        for (int u = 0; u < 2; ++u) {
            float4 v = *(const float4*)&sA[row * 132 + seg * 8 + u * 4];
            m += v.x + v.y + v.z + v.w;
            q = fmaf(v.x, v.x, q); q = fmaf(v.y, v.y, q);
            q = fmaf(v.z, v.z, q); q = fmaf(v.w, v.w, q);
        }
        m += __shfl_xor(m, 1); m += __shfl_xor(m, 2); m += __shfl_xor(m, 4); m += __shfl_xor(m, 8);
        q += __shfl_xor(q, 1); q += __shfl_xor(q, 2); q += __shfl_xor(q, 4); q += __shfl_xor(q, 8);
        float mean = m * (1.f / 128.f);
        float rstd = rsqrtf(q * (1.f / 128.f) - mean * mean + 1e-5f);
        if ((tid & 15) == 0) { sMean[row] = mean; sRstd[row] = rstd; }
    }
    __syncthreads();
    {   // P4: an2 = sigmoid(sn@Wg2+bg2)*LN(A) + sn@Ws2  (writes sAn2 = sAF)
        short8 wg2[4], ws2[4];
        #pragma unroll
        for (int kk = 0; kk < 4; ++kk) {
            wg2[kk] = WFRAG(Wg2t, 128, n0, kk);
            ws2[kk] = WFRAG(Ws2t, 128, n0, kk);
        }
        #pragma unroll
        for (int rt = 0; rt < 2; ++rt) {
            f32x4 ag = {0.f,0.f,0.f,0.f}, as = {0.f,0.f,0.f,0.f};
            #pragma unroll
            for (int kk = 0; kk < 4; ++kk) {
                short8 a = AFRAG(sSn, 136, rt * 16, kk);
                MFMA(ag, a, wg2[kk]);
                MFMA(as, a, ws2[kk]);
            }
            const int col = n0 + cl;
            float bg2c = bg2[col];
            #pragma unroll
            for (int i = 0; i < 4; ++i) {
                int r = rt * 16 + kg * 4 + i;
                float lnA = (sA[r * 132 + col] - sMean[r]) * sRstd[r];
                sAn2[r * 136 + col] = f2bf(sigmoidf_(ag[i] + bg2c) * lnA + as[i]);
            }
        }
    }
    __syncthreads();
    {   // P5: b = silu(an2@Wsw) * (an2@Wlin)  (writes sB over sS/sSn)
        short8 a2f[2][4];
        #pragma unroll
        for (int rt = 0; rt < 2; ++rt)
            #pragma unroll
            for (int kk = 0; kk < 4; ++kk)
                a2f[rt][kk] = AFRAG(sAn2, 136, rt * 16, kk);
        #pragma unroll
        for (int j = 0; j < 2; ++j) {
            const int n0b = w * 32 + j * 16;
            short8 ww[4], wl[4];
            #pragma unroll
            for (int kk = 0; kk < 4; ++kk) {
                ww[kk] = WFRAG(Wswt, 128, n0b, kk);
                wl[kk] = WFRAG(Wlint, 128, n0b, kk);
            }
            #pragma unroll
            for (int rt = 0; rt < 2; ++rt) {
                f32x4 aw = {0.f,0.f,0.f,0.f}, al = {0.f,0.f,0.f,0.f};
                #pragma unroll
                for (int kk = 0; kk < 4; ++kk) {
                    MFMA(aw, a2f[rt][kk], ww[kk]);
                    MFMA(al, a2f[rt][kk], wl[kk]);
                }
                const int col2 = n0b + cl;
                #pragma unroll
                for (int i = 0; i < 4; ++i) {
                    int r = rt * 16 + kg * 4 + i;
                    float x = aw[i];
                    float bb = (x / (1.f + expf(-x))) * al[i];
                    sB[r * 264 + col2] = f2bf(bb);
                }
            }
        }
    }
    __syncthreads();
    {   // P6: out = A + g2 * (b @ Wout2)
        short8 wo[8];
        #pragma unroll
        for (int kk = 0; kk < 8; ++kk) wo[kk] = WFRAG(Wout2t, 256, n0, kk);
        #pragma unroll
        for (int rt = 0; rt < 2; ++rt) {
            f32x4 acc = {0.f,0.f,0.f,0.f};
            #pragma unroll
            for (int kk = 0; kk < 8; ++kk) {
                short8 a = AFRAG(sB, 264, rt * 16, kk);
                MFMA(acc, a, wo[kk]);
            }
            const int col = n0 + cl;
            #pragma unroll
            for (int i = 0; i < 4; ++i) {
                int r = rt * 16 + kg * 4 + i;
                long t = t0 + r;
                Out[t * 128 + col] = sA[r * 132 + col] + g2s[rt * 4 + i] * acc[i];
            }
        }
    }
}

// ---------------------------------------------------------------------------
extern "C" void kernel_launch(void* const* d_in, const int* in_sizes, int n_in,
                              void* d_out, int out_size, void* d_ws, size_t ws_size,
                              hipStream_t stream)
{
    const float* A_I  = (const float*)d_in[0];
    const float* S_I  = (const float*)d_in[1];
    const float* Z    = (const float*)d_in[2];
    const float* maskK = (const float*)d_in[6];
    const float* a1Wg = (const float*)d_in[7];
    const float* a1bg = (const float*)d_in[8];
    const float* a1Ws = (const float*)d_in[9];
    const float* Wq   = (const float*)d_in[10];
    const float* bq   = (const float*)d_in[11];
    const float* Wk   = (const float*)d_in[12];
    const float* Wv   = (const float*)d_in[13];
    const float* ln0g = (const float*)d_in[14];
    const float* ln0b = (const float*)d_in[15];
    const float* Wb   = (const float*)d_in[16];
    const float* Wga  = (const float*)d_in[17];
    const float* Wa   = (const float*)d_in[18];
    const float* Wop  = (const float*)d_in[19];
    const float* bop  = (const float*)d_in[20];
    const float* a2Wg = (const float*)d_in[21];
    const float* a2bg = (const float*)d_in[22];
    const float* a2Ws = (const float*)d_in[23];
    const float* Wsw  = (const float*)d_in[24];
    const float* Wlin = (const float*)d_in[25];
    const float* ctWg = (const float*)d_in[26];
    const float* ctbg = (const float*)d_in[27];
    const float* Wout2 = (const float*)d_in[28];
    float* out = (float*)d_out;

    const size_t NTC = (size_t)DL * 128;   // 2,097,152 elems per (D,L,C) tensor
    short* Qb = (short*)d_ws;
    short* Kb = Qb + NTC;
    short* Vb = Kb + NTC;
    short* Gb = Vb + NTC;
    short* BBt = Gb + NTC;                 // [64][4][128][32] bf16 = 2 MB
    short* wbt = BBt + (size_t)NQB * 4 * 128 * 32;

    short* Wg1t = wbt + 0 * 16384;
    short* Ws1t = wbt + 1 * 16384;
    short* Wqt  = wbt + 2 * 16384;
    short* Wkt  = wbt + 3 * 16384;
    short* Wvt  = wbt + 4 * 16384;
    short* Wgat = wbt + 5 * 16384;
    short* Wat  = wbt + 6 * 16384;
    short* Wopt = wbt + 7 * 16384;
    short* ctWgt = wbt + 8 * 16384;
    short* Wg2t = wbt + 9 * 16384;
    short* Ws2t = wbt + 10 * 16384;
    short* Wswt = wbt + 180224;
    short* Wlint = wbt + 212992;
    short* Wout2t = wbt + 245760;

    k_prep<<<529, 256, 0, stream>>>(a1Wg, a1Ws, Wq, Wk, Wv, Wga, Wa, Wop, ctWg,
                                    a2Wg, a2Ws, Wsw, Wlin, Wout2,
                                    Z, ln0g, ln0b, Wb, wbt, BBt);
    k_adaln_qkvg<<<DL / 32, 512, 0, stream>>>(A_I, S_I, Wg1t, Ws1t, Wqt, Wkt, Wvt, Wgat,
                                              a1bg, bq, Qb, Kb, Vb, Gb);
    k_attn_postf<<<dim3(NQB, 8), 512, 0, stream>>>(Qb, Kb, Vb, Gb, BBt, maskK,
                                                   S_I, A_I,
                                                   Wat, Wopt, ctWgt, Wg2t, Ws2t,
                                                   Wswt, Wlint, Wout2t,
                                                   bop, ctbg, a2bg, out);
}